// Round 2
// baseline (387.832 us; speedup 1.0000x reference)
//
#include <hip/hip_runtime.h>
#include <stdint.h>

#define DIM 768
#define HDIM 3072

typedef unsigned short u16;
typedef unsigned char u8;
typedef unsigned int u32;
typedef __bf16 bf16x8 __attribute__((ext_vector_type(8)));
typedef float f32x2 __attribute__((ext_vector_type(2)));
typedef float f32x4 __attribute__((ext_vector_type(4)));
typedef float f32x16 __attribute__((ext_vector_type(16)));
typedef int i32x8 __attribute__((ext_vector_type(8)));

__device__ __forceinline__ u16 f2b(float f) {
    union { float f; unsigned i; } v; v.f = f;
    unsigned r = (v.i + 0x7FFFu + ((v.i >> 16) & 1u)) >> 16;
    return (u16)r;
}
__device__ __forceinline__ unsigned pack2b(float a, float b) {
    return (unsigned)f2b(a) | ((unsigned)f2b(b) << 16);
}
// tanh-form GELU via v_exp_f32 / v_rcp_f32 (max abs err vs exact ~1e-3)
__device__ __forceinline__ float gelu_f(float v) {
    float u = v * (1.5957691216f + 0.07135481627f * v * v);
    float e = __builtin_amdgcn_exp2f(-1.442695041f * u);
    return v * __builtin_amdgcn_rcpf(1.0f + e);
}
__device__ __forceinline__ void gl_lds16(const void* g, void* l) {
    __builtin_amdgcn_global_load_lds(
        (__attribute__((address_space(1))) void*)(g),
        (__attribute__((address_space(3))) void*)(l), 16, 0, 0);
}

// ---------- fp32 -> bf16 convert ----------
__global__ __launch_bounds__(256) void cvt_bf16(const float4* __restrict__ s,
                                                ushort4* __restrict__ d, int n4) {
    int i = blockIdx.x * 256 + threadIdx.x;
    if (i < n4) {
        float4 v = s[i];
        ushort4 o;
        o.x = f2b(v.x); o.y = f2b(v.y); o.z = f2b(v.z); o.w = f2b(v.w);
        d[i] = o;
    }
}

// ---------- fp32 -> fp8 e4m3 convert (4 floats -> 1 dword) ----------
__global__ __launch_bounds__(256) void cvt_fp8(const float4* __restrict__ s,
                                               unsigned* __restrict__ d, int n4) {
    int i = blockIdx.x * 256 + threadIdx.x;
    if (i < n4) {
        float4 v = s[i];
        int p = __builtin_amdgcn_cvt_pk_fp8_f32(v.x, v.y, 0, false);
        p = __builtin_amdgcn_cvt_pk_fp8_f32(v.z, v.w, p, true);
        d[i] = (unsigned)p;
    }
}

__global__ void pack_bias3(const float* __restrict__ a, const float* __restrict__ b,
                           const float* __restrict__ c, float* __restrict__ o) {
    int i = blockIdx.x * 256 + threadIdx.x;
    if (i < DIM) { o[i] = a[i]; o[i + DIM] = b[i]; o[i + 2 * DIM] = c[i]; }
}

// ---------- LayerNorm (ddof=1, eps on std), wave per row, fp8 output ----------
__global__ __launch_bounds__(256) void ln_rows_f8(const float* __restrict__ x, u8* __restrict__ xn,
                                                  const float* __restrict__ g, const float* __restrict__ b) {
    int row = blockIdx.x * 4 + (threadIdx.x >> 6);
    int lane = threadIdx.x & 63;
    const float* xr = x + (size_t)row * DIM + lane * 12;
    float v[12];
#pragma unroll
    for (int i = 0; i < 3; ++i) {
        float4 t = ((const float4*)xr)[i];
        v[i * 4 + 0] = t.x; v[i * 4 + 1] = t.y; v[i * 4 + 2] = t.z; v[i * 4 + 3] = t.w;
    }
    float s = 0.f, ss = 0.f;
#pragma unroll
    for (int i = 0; i < 12; ++i) { s += v[i]; ss += v[i] * v[i]; }
#pragma unroll
    for (int o = 32; o; o >>= 1) { s += __shfl_xor(s, o); ss += __shfl_xor(ss, o); }
    float mean = s * (1.f / DIM);
    float var = (ss - (float)DIM * mean * mean) * (1.f / (DIM - 1));
    float denom = sqrtf(var) + 1e-6f;
    float sc = g[0] / denom, bb = b[0] - mean * sc;
    unsigned* outp = (unsigned*)(xn + (size_t)row * DIM + lane * 12);
#pragma unroll
    for (int i = 0; i < 3; ++i) {
        int p = __builtin_amdgcn_cvt_pk_fp8_f32(v[i * 4 + 0] * sc + bb, v[i * 4 + 1] * sc + bb, 0, false);
        p = __builtin_amdgcn_cvt_pk_fp8_f32(v[i * 4 + 2] * sc + bb, v[i * 4 + 3] * sc + bb, p, true);
        outp[i] = (unsigned)p;
    }
}

// ---------- fp8 GEMM: C[M,N] = A[M,K] @ B[N,K]^T, MX MFMA w/ unit scales ----------
// BK=128, 128x128 tile, swapped mfma(B,A) -> C^T reg layout; coalesced stores
// via LDS-staged, 4B-XOR-swizzled C tile.
// EPI 0: acc+bias -> fp8 out       (QKV)
// EPI 2: acc+bias+resid -> f32 out (MLP down + residual), 2-pass 32KB staging
template <int EPI, int N, int K>
__global__ __launch_bounds__(256)
void gemm_f8(const u8* __restrict__ A, const u8* __restrict__ B,
             const float* __restrict__ bias, const float* __restrict__ resid,
             u8* __restrict__ Co, float* __restrict__ Cf) {
    __shared__ __align__(16) u8 smem[32768];
    u8* As = smem;
    u8* Bs = smem + 16384;
    const int tid = threadIdx.x, lane = tid & 63, wave = tid >> 6;
    const int row0 = blockIdx.x * 128, col0 = blockIdx.y * 128;
    const int wm = (wave >> 1) * 64, wn = (wave & 1) * 64;
    f32x16 acc[2][2] = {};

    const int srow = lane >> 3;
    const int schunk = ((lane & 7) ^ srow) * 16;
    const u8* Ag = A + (size_t)(row0 + wave * 8 + srow) * K + schunk;
    const u8* Bg = B + (size_t)(col0 + wave * 8 + srow) * K + schunk;
    const size_t s32 = (size_t)32 * K;
    u8* AsW = As + wave * 1024;
    u8* BsW = Bs + wave * 1024;

    const int r31 = lane & 31, khalf = lane >> 5;

    for (int kb = 0; kb < K; kb += 128) {
#pragma unroll
        for (int i = 0; i < 4; ++i) {
            gl_lds16(Ag + i * s32, AsW + i * 4096);
            gl_lds16(Bg + i * s32, BsW + i * 4096);
        }
        Ag += 128; Bg += 128;
        __syncthreads();
#pragma unroll
        for (int ks = 0; ks < 2; ++ks) {
            const int c0 = ks * 4 + khalf * 2;
            union { i32x8 v; uint4 q[2]; } af[2], bfr[2];
#pragma unroll
            for (int ib = 0; ib < 2; ++ib) {
                const int r = wm + ib * 32 + r31;
                const u8* base = As + r * 128;
                const int x7 = (r & 7);
                af[ib].q[0] = *(const uint4*)(base + ((c0 ^ x7) * 16));
                af[ib].q[1] = *(const uint4*)(base + (((c0 + 1) ^ x7) * 16));
            }
#pragma unroll
            for (int jb = 0; jb < 2; ++jb) {
                const int r = wn + jb * 32 + r31;
                const u8* base = Bs + r * 128;
                const int x7 = (r & 7);
                bfr[jb].q[0] = *(const uint4*)(base + ((c0 ^ x7) * 16));
                bfr[jb].q[1] = *(const uint4*)(base + (((c0 + 1) ^ x7) * 16));
            }
#pragma unroll
            for (int ib = 0; ib < 2; ++ib)
#pragma unroll
                for (int jb = 0; jb < 2; ++jb)
                    acc[ib][jb] = __builtin_amdgcn_mfma_scale_f32_32x32x64_f8f6f4(
                        bfr[jb].v, af[ib].v, acc[ib][jb], 0, 0,
                        0, 0x7F7F7F7F, 0, 0x7F7F7F7F);
        }
        __syncthreads();
    }
    // C^T frag: local row = wm+ib*32+r31, local col = wn+jb*32+gq*8+4*khalf+(reg&3)
    if (EPI == 0) {
        // stage packed fp8 tile (128 rows x 128B), dword-XOR swizzle
        u32* Cs = (u32*)smem;
#pragma unroll
        for (int ib = 0; ib < 2; ++ib) {
            const int row = wm + ib * 32 + r31;
            const int rx = row & 31;
#pragma unroll
            for (int jb = 0; jb < 2; ++jb)
#pragma unroll
                for (int gq = 0; gq < 4; ++gq) {
                    const int cb = wn + jb * 32 + gq * 8 + 4 * khalf;
                    float4 bv = *(const float4*)(bias + col0 + cb);
                    float v0 = acc[ib][jb][gq * 4 + 0] + bv.x;
                    float v1 = acc[ib][jb][gq * 4 + 1] + bv.y;
                    float v2 = acc[ib][jb][gq * 4 + 2] + bv.z;
                    float v3 = acc[ib][jb][gq * 4 + 3] + bv.w;
                    int p = __builtin_amdgcn_cvt_pk_fp8_f32(v0, v1, 0, false);
                    p = __builtin_amdgcn_cvt_pk_fp8_f32(v2, v3, p, true);
                    Cs[row * 32 + ((cb >> 2) ^ rx)] = (u32)p;
                }
        }
        __syncthreads();
#pragma unroll
        for (int pr = 0; pr < 4; ++pr) {
            const int r = pr * 32 + (tid >> 3);
            const int rx = r & 31;
            const int dwb = (tid & 7) * 4;
            uint4 o;
            o.x = Cs[r * 32 + ((dwb + 0) ^ rx)];
            o.y = Cs[r * 32 + ((dwb + 1) ^ rx)];
            o.z = Cs[r * 32 + ((dwb + 2) ^ rx)];
            o.w = Cs[r * 32 + ((dwb + 3) ^ rx)];
            *(uint4*)(Co + (size_t)(row0 + r) * N + col0 + dwb * 4) = o;
        }
    } else {
        // fp32 out + resid: 2-pass staging, 64 rows x 128 f32 (32KB), 16B-chunk swizzle
        float* Cs = (float*)smem;
#pragma unroll
        for (int pass = 0; pass < 2; ++pass) {
            const int ss = (wm >> 1) + r31;  // slot row 0..63
            const int sx = ss & 7;
#pragma unroll
            for (int jb = 0; jb < 2; ++jb)
#pragma unroll
                for (int gq = 0; gq < 4; ++gq) {
                    const int cb = wn + jb * 32 + gq * 8 + 4 * khalf;
                    float4 bv = *(const float4*)(bias + col0 + cb);
                    float4 v;
                    v.x = acc[pass][jb][gq * 4 + 0] + bv.x;
                    v.y = acc[pass][jb][gq * 4 + 1] + bv.y;
                    v.z = acc[pass][jb][gq * 4 + 2] + bv.z;
                    v.w = acc[pass][jb][gq * 4 + 3] + bv.w;
                    *(float4*)(Cs + ss * 128 + (((cb >> 2) ^ sx) << 2)) = v;
                }
            __syncthreads();
            const int s = tid >> 2;
            const int grow = row0 + (s >> 5) * 64 + pass * 32 + (s & 31);
#pragma unroll
            for (int k = 0; k < 8; ++k) {
                const int c = k * 4 + (tid & 3);
                float4 v = *(const float4*)(Cs + s * 128 + ((c ^ (s & 7)) << 2));
                const size_t gi = (size_t)grow * N + col0 + c * 4;
                float4 rv = *(const float4*)(resid + gi);
                v.x += rv.x; v.y += rv.y; v.z += rv.z; v.w += rv.w;
                *(float4*)(Cf + gi) = v;
            }
            if (pass == 0) __syncthreads();
        }
    }
}

// ---------- bf16 GEMM (MLP up), 256x256 tile, 8 waves, double-buffered LDS,
// counted-vmcnt pipeline (T3/T4-style), gelu epilogue, fp8 out ----------
template <int N, int K>
__global__ __launch_bounds__(512, 2)
void gemm_up2(const u16* __restrict__ A, const u16* __restrict__ B,
              const float* __restrict__ bias, u8* __restrict__ C8) {
    // LDS: A tiles [2][256][64] bf16 at 0, B tiles [2][256][64] bf16 at 32768 elems
    __shared__ __align__(16) u16 AB[65536];  // 128 KiB
    const int tid = threadIdx.x, lane = tid & 63, wave = tid >> 6;
    const int row0 = blockIdx.x * 256, col0 = blockIdx.y * 256;
    const int wr = wave >> 2, wc = wave & 3;       // 2M x 4N wave grid
    const int la = lane & 15, qd = lane >> 4;
    f32x4 acc[8][4] = {};

    const int srow = lane >> 3;            // 0..7
    const int sc = (lane & 7) ^ srow;      // pre-swizzled 16B chunk (both-sides XOR)
    const u16* Ag = A + (size_t)(row0 + wave * 8 + srow) * K + sc * 8;
    const u16* Bg = B + (size_t)(col0 + wave * 8 + srow) * K + sc * 8;
    const size_t s64r = (size_t)64 * K;
    u16* AlW = AB + wave * 512;            // (wave*8 rows) * 64 elems
    u16* BlW = AB + 32768 + wave * 512;
    constexpr int NT = K / 64;             // 12

    // stage K-tile t into buffer t&1 (8 global_load_lds per wave)
#define STAGE_UP(t)                                                         \
    {                                                                       \
        const int _b = (t) & 1;                                             \
        const u16* _ag = Ag + (size_t)(t) * 64;                             \
        const u16* _bg = Bg + (size_t)(t) * 64;                             \
        u16* _al = AlW + _b * 16384;                                        \
        u16* _bl = BlW + _b * 16384;                                        \
        _Pragma("unroll")                                                   \
        for (int _i = 0; _i < 4; ++_i) {                                    \
            gl_lds16(_ag + _i * s64r, _al + _i * 4096);                     \
            gl_lds16(_bg + _i * s64r, _bl + _i * 4096);                     \
        }                                                                   \
    }

    STAGE_UP(0);
    STAGE_UP(1);
    asm volatile("s_waitcnt vmcnt(8)" ::: "memory");  // tile0 landed, tile1 in flight
    asm volatile("s_barrier" ::: "memory");

    for (int kt = 0; kt < NT; ++kt) {
        const u16* Ab = AB + (kt & 1) * 16384;
        const u16* Bb = AB + 32768 + (kt & 1) * 16384;
        // B fragments for the whole tile (held in regs across all 4 phases)
        bf16x8 bf[4][2];
#pragma unroll
        for (int j = 0; j < 4; ++j) {
            const int br = wc * 64 + j * 16 + la;
            const int bx = br & 7;
#pragma unroll
            for (int ks = 0; ks < 2; ++ks)
                bf[j][ks] = *(const bf16x8*)(Bb + br * 64 + (((ks * 4 + qd) ^ bx) * 8));
        }
        // 4 quadrant phases: 2 row-frags x 4 col-frags x 2 kslices = 16 MFMA each
#pragma unroll
        for (int q = 0; q < 4; ++q) {
            bf16x8 af[2][2];
#pragma unroll
            for (int ii = 0; ii < 2; ++ii) {
                const int ar = wr * 128 + (q * 2 + ii) * 16 + la;
                const int ax = ar & 7;
#pragma unroll
                for (int ks = 0; ks < 2; ++ks)
                    af[ii][ks] = *(const bf16x8*)(Ab + ar * 64 + (((ks * 4 + qd) ^ ax) * 8));
            }
            __builtin_amdgcn_s_setprio(1);
#pragma unroll
            for (int ii = 0; ii < 2; ++ii)
#pragma unroll
                for (int j = 0; j < 4; ++j)
#pragma unroll
                    for (int ks = 0; ks < 2; ++ks)
                        acc[q * 2 + ii][j] = __builtin_amdgcn_mfma_f32_16x16x32_bf16(
                            bf[j][ks], af[ii][ks], acc[q * 2 + ii][j], 0, 0, 0);
            __builtin_amdgcn_s_setprio(0);
        }
        // all waves done reading buf[kt&1]
        asm volatile("s_barrier" ::: "memory");
        if (kt + 2 < NT) {
            STAGE_UP(kt + 2);  // into buf[kt&1] (just freed)
            // retire tile kt+1's 8 loads; leave kt+2's 8 in flight (counted, not 0)
            asm volatile("s_waitcnt vmcnt(8)" ::: "memory");
        } else {
            asm volatile("s_waitcnt vmcnt(0)" ::: "memory");
        }
        asm volatile("s_barrier" ::: "memory");
    }
#undef STAGE_UP

    // Epilogue: gelu(acc+bias) -> fp8, staged in LDS (256 rows x 64 dwords = 64KB),
    // dword-XOR swizzle, then coalesced uint4 stores.
    // C^T frag: local row = wr*128+i*16+la, local col = wc*64+j*16+qd*4+reg
    u32* Cs = (u32*)AB;
#pragma unroll
    for (int i = 0; i < 8; ++i) {
        const int row = wr * 128 + i * 16 + la;
        const int rx = row & 63;
#pragma unroll
        for (int j = 0; j < 4; ++j) {
            const int cb = wc * 64 + j * 16 + qd * 4;
            float4 bv = *(const float4*)(bias + col0 + cb);
            float v0 = gelu_f(acc[i][j][0] + bv.x);
            float v1 = gelu_f(acc[i][j][1] + bv.y);
            float v2 = gelu_f(acc[i][j][2] + bv.z);
            float v3 = gelu_f(acc[i][j][3] + bv.w);
            int p = __builtin_amdgcn_cvt_pk_fp8_f32(v0, v1, 0, false);
            p = __builtin_amdgcn_cvt_pk_fp8_f32(v2, v3, p, true);
            Cs[row * 64 + ((cb >> 2) ^ rx)] = (u32)p;
        }
    }
    __syncthreads();
#pragma unroll
    for (int pr = 0; pr < 4; ++pr) {
        const int r = pr * 64 + (tid >> 3);
        const int rx = r & 63;
        const int dwb = (tid & 7) * 8;
        uint4 o0, o1;
        o0.x = Cs[r * 64 + ((dwb + 0) ^ rx)];
        o0.y = Cs[r * 64 + ((dwb + 1) ^ rx)];
        o0.z = Cs[r * 64 + ((dwb + 2) ^ rx)];
        o0.w = Cs[r * 64 + ((dwb + 3) ^ rx)];
        o1.x = Cs[r * 64 + ((dwb + 4) ^ rx)];
        o1.y = Cs[r * 64 + ((dwb + 5) ^ rx)];
        o1.z = Cs[r * 64 + ((dwb + 6) ^ rx)];
        o1.w = Cs[r * 64 + ((dwb + 7) ^ rx)];
        u8* outp = C8 + (size_t)(row0 + r) * N + col0 + dwb * 4;
        *(uint4*)(outp) = o0;
        *(uint4*)(outp + 16) = o1;
    }
}

// ---------- attention (8-token groups, fp8 qkv) + residual + LN2 ----------
__global__ __launch_bounds__(256)
void attn_ln(const u8* __restrict__ qkv, const float* __restrict__ x,
             float* __restrict__ x1, u16* __restrict__ xn2,
             const float* __restrict__ g, const float* __restrict__ b) {
    __shared__ __align__(16) u8 sq[8 * 2304];
    __shared__ float sw[64];
    const int tid = threadIdx.x;
    const uint4* src = (const uint4*)(qkv + (size_t)blockIdx.x * (8 * 2304));
    uint4* dst = (uint4*)sq;
#pragma unroll
    for (int i = 0; i < 5; ++i) {
        int idx = tid + i * 256;
        if (idx < 1152) dst[idx] = src[idx];
    }
    __syncthreads();
    const u32* sq32 = (const u32*)sq;
    const int wave = tid >> 6, lane = tid & 63;
#pragma unroll 2
    for (int p = wave * 16; p < wave * 16 + 16; ++p) {
        const u32* qr = sq32 + (p >> 3) * 576 + lane * 3;
        const u32* kr = sq32 + (p & 7) * 576 + 192 + lane * 3;
        float s = 0.f;
#pragma unroll
        for (int i = 0; i < 3; ++i) {
            u32 qd = qr[i], kd = kr[i];
            f32x2 q0 = __builtin_amdgcn_cvt_pk_f32_fp8(qd, false);
            f32x2 q1 = __builtin_amdgcn_cvt_pk_f32_fp8(qd, true);
            f32x2 k0 = __builtin_amdgcn_cvt_pk_f32_fp8(kd, false);
            f32x2 k1 = __builtin_amdgcn_cvt_pk_f32_fp8(kd, true);
            s += q0[0] * k0[0] + q0[1] * k0[1] + q1[0] * k1[0] + q1[1] * k1[1];
        }
#pragma unroll
        for (int o = 32; o; o >>= 1) s += __shfl_xor(s, o);
        if (lane == 0) sw[p] = s;
    }
    __syncthreads();
    if (tid < 8) {
        const float scl = 0.03608439182435161f; // 1/sqrt(768)
        float e[8]; float m = -1e30f;
#pragma unroll
        for (int j = 0; j < 8; ++j) m = fmaxf(m, sw[tid * 8 + j]);
        float sum = 0.f;
#pragma unroll
        for (int j = 0; j < 8; ++j) { e[j] = expf((sw[tid * 8 + j] - m) * scl); sum += e[j]; }
        float inv = 1.f / sum;
#pragma unroll
        for (int j = 0; j < 8; ++j) sw[tid * 8 + j] = e[j] * inv;
    }
    __syncthreads();
    const int h = tid >> 5, li = tid & 31;
    float w[8];
#pragma unroll
    for (int kk = 0; kk < 8; ++kk) w[kk] = sw[h * 8 + kk];
    const size_t trow = (size_t)blockIdx.x * 8 + h;
    const float* xr = x + trow * DIM;
    float* x1r = x1 + trow * DIM;
    float xv[24], s = 0.f, ss = 0.f;
#pragma unroll
    for (int wd = 0; wd < 3; ++wd) {
        const int d0 = wd * 256 + li * 8;
        float o[8] = {};
#pragma unroll
        for (int kk = 0; kk < 8; ++kk) {
            uint2 vv = *(const uint2*)(sq32 + kk * 576 + 384 + wd * 64 + li * 2);
            f32x2 a0 = __builtin_amdgcn_cvt_pk_f32_fp8(vv.x, false);
            f32x2 a1 = __builtin_amdgcn_cvt_pk_f32_fp8(vv.x, true);
            f32x2 a2 = __builtin_amdgcn_cvt_pk_f32_fp8(vv.y, false);
            f32x2 a3 = __builtin_amdgcn_cvt_pk_f32_fp8(vv.y, true);
            o[0] += w[kk] * a0[0]; o[1] += w[kk] * a0[1];
            o[2] += w[kk] * a1[0]; o[3] += w[kk] * a1[1];
            o[4] += w[kk] * a2[0]; o[5] += w[kk] * a2[1];
            o[6] += w[kk] * a3[0]; o[7] += w[kk] * a3[1];
        }
        float4 xa = *(const float4*)(xr + d0);
        float4 xb = *(const float4*)(xr + d0 + 4);
        float vals[8] = { o[0] + xa.x, o[1] + xa.y, o[2] + xa.z, o[3] + xa.w,
                          o[4] + xb.x, o[5] + xb.y, o[6] + xb.z, o[7] + xb.w };
        float4 w0, w1;
        w0.x = vals[0]; w0.y = vals[1]; w0.z = vals[2]; w0.w = vals[3];
        w1.x = vals[4]; w1.y = vals[5]; w1.z = vals[6]; w1.w = vals[7];
        *(float4*)(x1r + d0) = w0;
        *(float4*)(x1r + d0 + 4) = w1;
#pragma unroll
        for (int e = 0; e < 8; ++e) {
            xv[wd * 8 + e] = vals[e];
            s += vals[e]; ss += vals[e] * vals[e];
        }
    }
#pragma unroll
    for (int o2 = 16; o2; o2 >>= 1) { s += __shfl_xor(s, o2); ss += __shfl_xor(ss, o2); }
    float mean = s * (1.f / 768.f);
    float var = (ss - 768.f * mean * mean) * (1.f / 767.f);
    float denom = sqrtf(var) + 1e-6f;
    float sc = g[0] / denom, bb = b[0] - mean * sc;
    u16* xnr = xn2 + trow * DIM;
#pragma unroll
    for (int wd = 0; wd < 3; ++wd) {
        const int d0 = wd * 256 + li * 8;
        uint4 o;
        o.x = pack2b(xv[wd * 8 + 0] * sc + bb, xv[wd * 8 + 1] * sc + bb);
        o.y = pack2b(xv[wd * 8 + 2] * sc + bb, xv[wd * 8 + 3] * sc + bb);
        o.z = pack2b(xv[wd * 8 + 4] * sc + bb, xv[wd * 8 + 5] * sc + bb);
        o.w = pack2b(xv[wd * 8 + 6] * sc + bb, xv[wd * 8 + 7] * sc + bb);
        *(uint4*)(xnr + d0) = o;
    }
}

extern "C" void kernel_launch(void* const* d_in, const int* in_sizes, int n_in,
                              void* d_out, int out_size, void* d_ws, size_t ws_size,
                              hipStream_t stream) {
    (void)n_in; (void)out_size; (void)ws_size;
    const float* x    = (const float*)d_in[0];
    const float* wq_w = (const float*)d_in[1];
    const float* wq_b = (const float*)d_in[2];
    const float* wk_w = (const float*)d_in[3];
    const float* wk_b = (const float*)d_in[4];
    const float* wv_w = (const float*)d_in[5];
    const float* wv_b = (const float*)d_in[6];
    const float* d1_w = (const float*)d_in[7];
    const float* d1_b = (const float*)d_in[8];
    const float* d2_w = (const float*)d_in[9];
    const float* d2_b = (const float*)d_in[10];
    const float* g1 = (const float*)d_in[11];
    const float* b1 = (const float*)d_in[12];
    const float* g2 = (const float*)d_in[13];
    const float* b2 = (const float*)d_in[14];
    float* out = (float*)d_out;
    char* ws = (char*)d_ws;

    const int T = in_sizes[0] / DIM;  // 16384

    // ws layout (bytes):
    u8*    w_qkv8 = (u8*)(ws);                    // [2304][768] fp8    1,769,472
    u16*   w_d1   = (u16*)(ws + 1769472);         // [3072][768] bf16   4,718,592
    u8*    w_d28  = (u8*)(ws + 6488064);          // [768][3072] fp8    2,359,296
    float* b_qkv  = (float*)(ws + 8847360);       // [2304] f32             9,216
    u16*   xn2    = (u16*)(ws + 8856576);         // [T][768] bf16     25,165,824
    float* x1     = (float*)(ws + 34022400);      // [T][768] f32      50,331,648
    u8*    xn1_8  = (u8*)(ws + 34022400);         // [T][768] fp8 — aliases x1 (dead before attn)
    u8*    qkv8   = (u8*)(ws + 84354048);         // [T][2304] fp8     37,748,736
    u8*    h8     = (u8*)(ws + 84354048);         // [T][3072] fp8 — reuses qkv region (dead after attn)

    cvt_fp8<<<576, 256, 0, stream>>>((const float4*)wq_w, (unsigned*)w_qkv8, 147456);
    cvt_fp8<<<576, 256, 0, stream>>>((const float4*)wk_w, (unsigned*)(w_qkv8 + 589824), 147456);
    cvt_fp8<<<576, 256, 0, stream>>>((const float4*)wv_w, (unsigned*)(w_qkv8 + 1179648), 147456);
    cvt_bf16<<<2304, 256, 0, stream>>>((const float4*)d1_w, (ushort4*)w_d1, 589824);
    cvt_fp8<<<2304, 256, 0, stream>>>((const float4*)d2_w, (unsigned*)w_d28, 589824);
    pack_bias3<<<3, 256, 0, stream>>>(wq_b, wk_b, wv_b, b_qkv);

    ln_rows_f8<<<T / 4, 256, 0, stream>>>(x, xn1_8, g1, b1);
    gemm_f8<0, 2304, 768><<<dim3(T / 128, 18), 256, 0, stream>>>(xn1_8, w_qkv8, b_qkv, nullptr, qkv8, nullptr);
    attn_ln<<<T / 8, 256, 0, stream>>>(qkv8, x, x1, xn2, g2, b2);
    gemm_up2<3072, 768><<<dim3(T / 256, 12), 512, 0, stream>>>(xn2, w_d1, d1_b, h8);
    gemm_f8<2, 768, 3072><<<dim3(T / 128, 6), 256, 0, stream>>>(h8, w_d28, d2_b, x1, nullptr, out);
}

// Round 6
// 374.366 us; speedup vs baseline: 1.0360x; 1.0360x over previous
//
#include <hip/hip_runtime.h>
#include <stdint.h>

#define DIM 768
#define HDIM 3072

typedef unsigned short u16;
typedef unsigned char u8;
typedef unsigned int u32;
typedef __bf16 bf16x8 __attribute__((ext_vector_type(8)));
typedef float f32x2 __attribute__((ext_vector_type(2)));
typedef float f32x4 __attribute__((ext_vector_type(4)));
typedef float f32x16 __attribute__((ext_vector_type(16)));
typedef int i32x8 __attribute__((ext_vector_type(8)));

__device__ __forceinline__ u16 f2b(float f) {
    union { float f; unsigned i; } v; v.f = f;
    unsigned r = (v.i + 0x7FFFu + ((v.i >> 16) & 1u)) >> 16;
    return (u16)r;
}
__device__ __forceinline__ unsigned pack2b(float a, float b) {
    return (unsigned)f2b(a) | ((unsigned)f2b(b) << 16);
}
// tanh-form GELU via v_exp_f32 / v_rcp_f32 (max abs err vs exact ~1e-3)
__device__ __forceinline__ float gelu_f(float v) {
    float u = v * (1.5957691216f + 0.07135481627f * v * v);
    float e = __builtin_amdgcn_exp2f(-1.442695041f * u);
    return v * __builtin_amdgcn_rcpf(1.0f + e);
}
__device__ __forceinline__ void gl_lds16(const void* g, void* l) {
    __builtin_amdgcn_global_load_lds(
        (__attribute__((address_space(1))) void*)(g),
        (__attribute__((address_space(3))) void*)(l), 16, 0, 0);
}

// ---------- merged weight-convert + bias-pack (one launch) ----------
// y=0: d1_w f32->bf16 (589824 f4);  y=1: d2_w f32->fp8 (589824 f4);
// y=2: wq/wk/wv f32->fp8 (3x147456 f4) + qkv bias pack (576 f4-slots).
__global__ __launch_bounds__(256) void cvt_all(
    const float4* __restrict__ wq, const float4* __restrict__ wk, const float4* __restrict__ wv,
    const float4* __restrict__ d1, const float4* __restrict__ d2,
    const float* __restrict__ bq, const float* __restrict__ bk, const float* __restrict__ bv,
    ushort4* __restrict__ o_d1, unsigned* __restrict__ o_d2,
    unsigned* __restrict__ o_qkv, float* __restrict__ o_bias) {
    const int i = blockIdx.x * 256 + threadIdx.x;
    const int y = blockIdx.y;
    if (y == 0) {
        float4 v = d1[i];
        ushort4 o;
        o.x = f2b(v.x); o.y = f2b(v.y); o.z = f2b(v.z); o.w = f2b(v.w);
        o_d1[i] = o;
    } else if (y == 1) {
        float4 v = d2[i];
        int p = __builtin_amdgcn_cvt_pk_fp8_f32(v.x, v.y, 0, false);
        p = __builtin_amdgcn_cvt_pk_fp8_f32(v.z, v.w, p, true);
        o_d2[i] = (unsigned)p;
    } else {
        if (i < 442368) {
            float4 v = (i < 147456) ? wq[i] : (i < 294912 ? wk[i - 147456] : wv[i - 294912]);
            int p = __builtin_amdgcn_cvt_pk_fp8_f32(v.x, v.y, 0, false);
            p = __builtin_amdgcn_cvt_pk_fp8_f32(v.z, v.w, p, true);
            o_qkv[i] = (unsigned)p;
        } else if (i < 442944) {
            const int j = (i - 442368) * 4;
#pragma unroll
            for (int e = 0; e < 4; ++e) {
                int f = j + e;
                float v = (f < 768) ? bq[f] : (f < 1536 ? bk[f - 768] : bv[f - 1536]);
                o_bias[f] = v;
            }
        }
    }
}

// ---------- LayerNorm (ddof=1, eps on std), wave per row, fp8 output ----------
__global__ __launch_bounds__(256) void ln_rows_f8(const float* __restrict__ x, u8* __restrict__ xn,
                                                  const float* __restrict__ g, const float* __restrict__ b) {
    int row = blockIdx.x * 4 + (threadIdx.x >> 6);
    int lane = threadIdx.x & 63;
    const float* xr = x + (size_t)row * DIM + lane * 12;
    float v[12];
#pragma unroll
    for (int i = 0; i < 3; ++i) {
        float4 t = ((const float4*)xr)[i];
        v[i * 4 + 0] = t.x; v[i * 4 + 1] = t.y; v[i * 4 + 2] = t.z; v[i * 4 + 3] = t.w;
    }
    float s = 0.f, ss = 0.f;
#pragma unroll
    for (int i = 0; i < 12; ++i) { s += v[i]; ss += v[i] * v[i]; }
#pragma unroll
    for (int o = 32; o; o >>= 1) { s += __shfl_xor(s, o); ss += __shfl_xor(ss, o); }
    float mean = s * (1.f / DIM);
    float var = (ss - (float)DIM * mean * mean) * (1.f / (DIM - 1));
    float denom = sqrtf(var) + 1e-6f;
    float sc = g[0] / denom, bb = b[0] - mean * sc;
    unsigned* outp = (unsigned*)(xn + (size_t)row * DIM + lane * 12);
#pragma unroll
    for (int i = 0; i < 3; ++i) {
        int p = __builtin_amdgcn_cvt_pk_fp8_f32(v[i * 4 + 0] * sc + bb, v[i * 4 + 1] * sc + bb, 0, false);
        p = __builtin_amdgcn_cvt_pk_fp8_f32(v[i * 4 + 2] * sc + bb, v[i * 4 + 3] * sc + bb, p, true);
        outp[i] = (unsigned)p;
    }
}

// ---------- fp8 GEMM: C[M,N] = A[M,K] @ B[N,K]^T, MX MFMA w/ unit scales ----------
// BK=128, 128x128 tile, swapped mfma(B,A) -> C^T reg layout; coalesced stores
// via LDS-staged, 4B-XOR-swizzled C tile.
// EPI 0: acc+bias -> fp8 out       (QKV)
// EPI 2: acc+bias+resid -> f32 out (MLP down + residual), 2-pass 32KB staging
template <int EPI, int N, int K>
__global__ __launch_bounds__(256)
void gemm_f8(const u8* __restrict__ A, const u8* __restrict__ B,
             const float* __restrict__ bias, const float* __restrict__ resid,
             u8* __restrict__ Co, float* __restrict__ Cf) {
    __shared__ __align__(16) u8 smem[32768];
    u8* As = smem;
    u8* Bs = smem + 16384;
    const int tid = threadIdx.x, lane = tid & 63, wave = tid >> 6;
    const int row0 = blockIdx.x * 128, col0 = blockIdx.y * 128;
    const int wm = (wave >> 1) * 64, wn = (wave & 1) * 64;
    f32x16 acc[2][2] = {};

    const int srow = lane >> 3;
    const int schunk = ((lane & 7) ^ srow) * 16;
    const u8* Ag = A + (size_t)(row0 + wave * 8 + srow) * K + schunk;
    const u8* Bg = B + (size_t)(col0 + wave * 8 + srow) * K + schunk;
    const size_t s32 = (size_t)32 * K;
    u8* AsW = As + wave * 1024;
    u8* BsW = Bs + wave * 1024;

    const int r31 = lane & 31, khalf = lane >> 5;

    for (int kb = 0; kb < K; kb += 128) {
#pragma unroll
        for (int i = 0; i < 4; ++i) {
            gl_lds16(Ag + i * s32, AsW + i * 4096);
            gl_lds16(Bg + i * s32, BsW + i * 4096);
        }
        Ag += 128; Bg += 128;
        __syncthreads();
#pragma unroll
        for (int ks = 0; ks < 2; ++ks) {
            const int c0 = ks * 4 + khalf * 2;
            union { i32x8 v; uint4 q[2]; } af[2], bfr[2];
#pragma unroll
            for (int ib = 0; ib < 2; ++ib) {
                const int r = wm + ib * 32 + r31;
                const u8* base = As + r * 128;
                const int x7 = (r & 7);
                af[ib].q[0] = *(const uint4*)(base + ((c0 ^ x7) * 16));
                af[ib].q[1] = *(const uint4*)(base + (((c0 + 1) ^ x7) * 16));
            }
#pragma unroll
            for (int jb = 0; jb < 2; ++jb) {
                const int r = wn + jb * 32 + r31;
                const u8* base = Bs + r * 128;
                const int x7 = (r & 7);
                bfr[jb].q[0] = *(const uint4*)(base + ((c0 ^ x7) * 16));
                bfr[jb].q[1] = *(const uint4*)(base + (((c0 + 1) ^ x7) * 16));
            }
#pragma unroll
            for (int ib = 0; ib < 2; ++ib)
#pragma unroll
                for (int jb = 0; jb < 2; ++jb)
                    acc[ib][jb] = __builtin_amdgcn_mfma_scale_f32_32x32x64_f8f6f4(
                        bfr[jb].v, af[ib].v, acc[ib][jb], 0, 0,
                        0, 0x7F7F7F7F, 0, 0x7F7F7F7F);
        }
        __syncthreads();
    }
    // C^T frag: local row = wm+ib*32+r31, local col = wn+jb*32+gq*8+4*khalf+(reg&3)
    if (EPI == 0) {
        // stage packed fp8 tile (128 rows x 128B), dword-XOR swizzle
        u32* Cs = (u32*)smem;
#pragma unroll
        for (int ib = 0; ib < 2; ++ib) {
            const int row = wm + ib * 32 + r31;
            const int rx = row & 31;
#pragma unroll
            for (int jb = 0; jb < 2; ++jb)
#pragma unroll
                for (int gq = 0; gq < 4; ++gq) {
                    const int cb = wn + jb * 32 + gq * 8 + 4 * khalf;
                    float4 bv = *(const float4*)(bias + col0 + cb);
                    float v0 = acc[ib][jb][gq * 4 + 0] + bv.x;
                    float v1 = acc[ib][jb][gq * 4 + 1] + bv.y;
                    float v2 = acc[ib][jb][gq * 4 + 2] + bv.z;
                    float v3 = acc[ib][jb][gq * 4 + 3] + bv.w;
                    int p = __builtin_amdgcn_cvt_pk_fp8_f32(v0, v1, 0, false);
                    p = __builtin_amdgcn_cvt_pk_fp8_f32(v2, v3, p, true);
                    Cs[row * 32 + ((cb >> 2) ^ rx)] = (u32)p;
                }
        }
        __syncthreads();
#pragma unroll
        for (int pr = 0; pr < 4; ++pr) {
            const int r = pr * 32 + (tid >> 3);
            const int rx = r & 31;
            const int dwb = (tid & 7) * 4;
            uint4 o;
            o.x = Cs[r * 32 + ((dwb + 0) ^ rx)];
            o.y = Cs[r * 32 + ((dwb + 1) ^ rx)];
            o.z = Cs[r * 32 + ((dwb + 2) ^ rx)];
            o.w = Cs[r * 32 + ((dwb + 3) ^ rx)];
            *(uint4*)(Co + (size_t)(row0 + r) * N + col0 + dwb * 4) = o;
        }
    } else {
        // fp32 out + resid: 2-pass staging, 64 rows x 128 f32 (32KB), 16B-chunk swizzle
        float* Cs = (float*)smem;
#pragma unroll
        for (int pass = 0; pass < 2; ++pass) {
            const int ss = (wm >> 1) + r31;  // slot row 0..63
            const int sx = ss & 7;
#pragma unroll
            for (int jb = 0; jb < 2; ++jb)
#pragma unroll
                for (int gq = 0; gq < 4; ++gq) {
                    const int cb = wn + jb * 32 + gq * 8 + 4 * khalf;
                    float4 bv = *(const float4*)(bias + col0 + cb);
                    float4 v;
                    v.x = acc[pass][jb][gq * 4 + 0] + bv.x;
                    v.y = acc[pass][jb][gq * 4 + 1] + bv.y;
                    v.z = acc[pass][jb][gq * 4 + 2] + bv.z;
                    v.w = acc[pass][jb][gq * 4 + 3] + bv.w;
                    *(float4*)(Cs + ss * 128 + (((cb >> 2) ^ sx) << 2)) = v;
                }
            __syncthreads();
            const int s = tid >> 2;
            const int grow = row0 + (s >> 5) * 64 + pass * 32 + (s & 31);
#pragma unroll
            for (int k = 0; k < 8; ++k) {
                const int c = k * 4 + (tid & 3);
                float4 v = *(const float4*)(Cs + s * 128 + ((c ^ (s & 7)) << 2));
                const size_t gi = (size_t)grow * N + col0 + c * 4;
                float4 rv = *(const float4*)(resid + gi);
                v.x += rv.x; v.y += rv.y; v.z += rv.z; v.w += rv.w;
                *(float4*)(Cf + gi) = v;
            }
            if (pass == 0) __syncthreads();
        }
    }
}

// ---------- bf16 GEMM (MLP up): gelu epilogue, fp8 out via staged coalesced stores ----------
// (round-0 verified version: 128x128 tile, 2-phase; the 256²/8-phase rewrites
// failed deterministically 3x with identical absmax — reverted per decision rule)
template <int N, int K>
__global__ __launch_bounds__(256)
void gemm_up(const u16* __restrict__ A, const u16* __restrict__ B,
             const float* __restrict__ bias, u8* __restrict__ C8) {
    __shared__ __align__(16) u16 As[128 * 64];
    __shared__ __align__(16) u16 Bs[128 * 64];
    const int tid = threadIdx.x;
    const int row0 = blockIdx.x * 128, col0 = blockIdx.y * 128;
    const int lane = tid & 63, wave = tid >> 6;
    const int wm = (wave >> 1) * 64, wn = (wave & 1) * 64;
    const int la = lane & 15, qd = lane >> 4;
    f32x4 acc[4][4] = {};

    const int srow = lane >> 3;
    const int schunk = (lane & 7) ^ srow;
    const u16* Ag = A + (size_t)(row0 + wave * 8 + srow) * K + schunk * 8;
    const u16* Bg = B + (size_t)(col0 + wave * 8 + srow) * K + schunk * 8;
    const size_t s32 = (size_t)32 * K;
    u16* AsW = &As[wave * 512];
    u16* BsW = &Bs[wave * 512];
    const int x7 = la & 7;

    for (int kb = 0; kb < K; kb += 64) {
#pragma unroll
        for (int i = 0; i < 4; ++i) {
            gl_lds16(Ag + i * s32, AsW + i * 2048);
            gl_lds16(Bg + i * s32, BsW + i * 2048);
        }
        Ag += 64; Bg += 64;
        __syncthreads();
#pragma unroll
        for (int ks = 0; ks < 2; ++ks) {
            const int cp = ((ks * 4 + qd) ^ x7) * 8;
            bf16x8 af[4], bfr[4];
#pragma unroll
            for (int i = 0; i < 4; ++i)
                af[i] = *(const bf16x8*)(&As[(wm + i * 16 + la) * 64 + cp]);
#pragma unroll
            for (int j = 0; j < 4; ++j)
                bfr[j] = *(const bf16x8*)(&Bs[(wn + j * 16 + la) * 64 + cp]);
#pragma unroll
            for (int i = 0; i < 4; ++i)
#pragma unroll
                for (int j = 0; j < 4; ++j)
                    acc[i][j] = __builtin_amdgcn_mfma_f32_16x16x32_bf16(bfr[j], af[i], acc[i][j], 0, 0, 0);
        }
        __syncthreads();
    }
    // C^T frag: local row = wm+i*16+la, local col = wn+j*16+qd*4+reg
    u32* Cs = (u32*)As;  // 16KB fp8 tile stage
#pragma unroll
    for (int i = 0; i < 4; ++i) {
        const int row = wm + i * 16 + la;
        const int rx = row & 31;
#pragma unroll
        for (int j = 0; j < 4; ++j) {
            const int cb = wn + j * 16 + qd * 4;
            float4 bv = *(const float4*)(bias + col0 + cb);
            float v0 = gelu_f(acc[i][j][0] + bv.x);
            float v1 = gelu_f(acc[i][j][1] + bv.y);
            float v2 = gelu_f(acc[i][j][2] + bv.z);
            float v3 = gelu_f(acc[i][j][3] + bv.w);
            int p = __builtin_amdgcn_cvt_pk_fp8_f32(v0, v1, 0, false);
            p = __builtin_amdgcn_cvt_pk_fp8_f32(v2, v3, p, true);
            Cs[row * 32 + ((cb >> 2) ^ rx)] = (u32)p;
        }
    }
    __syncthreads();
#pragma unroll
    for (int pr = 0; pr < 4; ++pr) {
        const int r = pr * 32 + (tid >> 3);
        const int rx = r & 31;
        const int dwb = (tid & 7) * 4;
        uint4 o;
        o.x = Cs[r * 32 + ((dwb + 0) ^ rx)];
        o.y = Cs[r * 32 + ((dwb + 1) ^ rx)];
        o.z = Cs[r * 32 + ((dwb + 2) ^ rx)];
        o.w = Cs[r * 32 + ((dwb + 3) ^ rx)];
        *(uint4*)(C8 + (size_t)(row0 + r) * N + col0 + dwb * 4) = o;
    }
}

// ---------- attention (8-token groups, fp8 qkv) + residual + LN2 ----------
__global__ __launch_bounds__(256)
void attn_ln(const u8* __restrict__ qkv, const float* __restrict__ x,
             float* __restrict__ x1, u16* __restrict__ xn2,
             const float* __restrict__ g, const float* __restrict__ b) {
    __shared__ __align__(16) u8 sq[8 * 2304];
    __shared__ float sw[64];
    const int tid = threadIdx.x;
    const uint4* src = (const uint4*)(qkv + (size_t)blockIdx.x * (8 * 2304));
    uint4* dst = (uint4*)sq;
#pragma unroll
    for (int i = 0; i < 5; ++i) {
        int idx = tid + i * 256;
        if (idx < 1152) dst[idx] = src[idx];
    }
    __syncthreads();
    const u32* sq32 = (const u32*)sq;
    const int wave = tid >> 6, lane = tid & 63;
#pragma unroll 2
    for (int p = wave * 16; p < wave * 16 + 16; ++p) {
        const u32* qr = sq32 + (p >> 3) * 576 + lane * 3;
        const u32* kr = sq32 + (p & 7) * 576 + 192 + lane * 3;
        float s = 0.f;
#pragma unroll
        for (int i = 0; i < 3; ++i) {
            u32 qd = qr[i], kd = kr[i];
            f32x2 q0 = __builtin_amdgcn_cvt_pk_f32_fp8(qd, false);
            f32x2 q1 = __builtin_amdgcn_cvt_pk_f32_fp8(qd, true);
            f32x2 k0 = __builtin_amdgcn_cvt_pk_f32_fp8(kd, false);
            f32x2 k1 = __builtin_amdgcn_cvt_pk_f32_fp8(kd, true);
            s += q0[0] * k0[0] + q0[1] * k0[1] + q1[0] * k1[0] + q1[1] * k1[1];
        }
#pragma unroll
        for (int o = 32; o; o >>= 1) s += __shfl_xor(s, o);
        if (lane == 0) sw[p] = s;
    }
    __syncthreads();
    if (tid < 8) {
        const float scl = 0.03608439182435161f; // 1/sqrt(768)
        float e[8]; float m = -1e30f;
#pragma unroll
        for (int j = 0; j < 8; ++j) m = fmaxf(m, sw[tid * 8 + j]);
        float sum = 0.f;
#pragma unroll
        for (int j = 0; j < 8; ++j) { e[j] = expf((sw[tid * 8 + j] - m) * scl); sum += e[j]; }
        float inv = 1.f / sum;
#pragma unroll
        for (int j = 0; j < 8; ++j) sw[tid * 8 + j] = e[j] * inv;
    }
    __syncthreads();
    const int h = tid >> 5, li = tid & 31;
    float w[8];
#pragma unroll
    for (int kk = 0; kk < 8; ++kk) w[kk] = sw[h * 8 + kk];
    const size_t trow = (size_t)blockIdx.x * 8 + h;
    const float* xr = x + trow * DIM;
    float* x1r = x1 + trow * DIM;
    float xv[24], s = 0.f, ss = 0.f;
#pragma unroll
    for (int wd = 0; wd < 3; ++wd) {
        const int d0 = wd * 256 + li * 8;
        float o[8] = {};
#pragma unroll
        for (int kk = 0; kk < 8; ++kk) {
            uint2 vv = *(const uint2*)(sq32 + kk * 576 + 384 + wd * 64 + li * 2);
            f32x2 a0 = __builtin_amdgcn_cvt_pk_f32_fp8(vv.x, false);
            f32x2 a1 = __builtin_amdgcn_cvt_pk_f32_fp8(vv.x, true);
            f32x2 a2 = __builtin_amdgcn_cvt_pk_f32_fp8(vv.y, false);
            f32x2 a3 = __builtin_amdgcn_cvt_pk_f32_fp8(vv.y, true);
            o[0] += w[kk] * a0[0]; o[1] += w[kk] * a0[1];
            o[2] += w[kk] * a1[0]; o[3] += w[kk] * a1[1];
            o[4] += w[kk] * a2[0]; o[5] += w[kk] * a2[1];
            o[6] += w[kk] * a3[0]; o[7] += w[kk] * a3[1];
        }
        float4 xa = *(const float4*)(xr + d0);
        float4 xb = *(const float4*)(xr + d0 + 4);
        float vals[8] = { o[0] + xa.x, o[1] + xa.y, o[2] + xa.z, o[3] + xa.w,
                          o[4] + xb.x, o[5] + xb.y, o[6] + xb.z, o[7] + xb.w };
        float4 w0, w1;
        w0.x = vals[0]; w0.y = vals[1]; w0.z = vals[2]; w0.w = vals[3];
        w1.x = vals[4]; w1.y = vals[5]; w1.z = vals[6]; w1.w = vals[7];
        *(float4*)(x1r + d0) = w0;
        *(float4*)(x1r + d0 + 4) = w1;
#pragma unroll
        for (int e = 0; e < 8; ++e) {
            xv[wd * 8 + e] = vals[e];
            s += vals[e]; ss += vals[e] * vals[e];
        }
    }
#pragma unroll
    for (int o2 = 16; o2; o2 >>= 1) { s += __shfl_xor(s, o2); ss += __shfl_xor(ss, o2); }
    float mean = s * (1.f / 768.f);
    float var = (ss - 768.f * mean * mean) * (1.f / 767.f);
    float denom = sqrtf(var) + 1e-6f;
    float sc = g[0] / denom, bb = b[0] - mean * sc;
    u16* xnr = xn2 + trow * DIM;
#pragma unroll
    for (int wd = 0; wd < 3; ++wd) {
        const int d0 = wd * 256 + li * 8;
        uint4 o;
        o.x = pack2b(xv[wd * 8 + 0] * sc + bb, xv[wd * 8 + 1] * sc + bb);
        o.y = pack2b(xv[wd * 8 + 2] * sc + bb, xv[wd * 8 + 3] * sc + bb);
        o.z = pack2b(xv[wd * 8 + 4] * sc + bb, xv[wd * 8 + 5] * sc + bb);
        o.w = pack2b(xv[wd * 8 + 6] * sc + bb, xv[wd * 8 + 7] * sc + bb);
        *(uint4*)(xnr + d0) = o;
    }
}

extern "C" void kernel_launch(void* const* d_in, const int* in_sizes, int n_in,
                              void* d_out, int out_size, void* d_ws, size_t ws_size,
                              hipStream_t stream) {
    (void)n_in; (void)out_size; (void)ws_size;
    const float* x    = (const float*)d_in[0];
    const float* wq_w = (const float*)d_in[1];
    const float* wq_b = (const float*)d_in[2];
    const float* wk_w = (const float*)d_in[3];
    const float* wk_b = (const float*)d_in[4];
    const float* wv_w = (const float*)d_in[5];
    const float* wv_b = (const float*)d_in[6];
    const float* d1_w = (const float*)d_in[7];
    const float* d1_b = (const float*)d_in[8];
    const float* d2_w = (const float*)d_in[9];
    const float* d2_b = (const float*)d_in[10];
    const float* g1 = (const float*)d_in[11];
    const float* b1 = (const float*)d_in[12];
    const float* g2 = (const float*)d_in[13];
    const float* b2 = (const float*)d_in[14];
    float* out = (float*)d_out;
    char* ws = (char*)d_ws;

    const int T = in_sizes[0] / DIM;  // 16384

    // ws layout (bytes):
    u8*    w_qkv8 = (u8*)(ws);                    // [2304][768] fp8    1,769,472
    u16*   w_d1   = (u16*)(ws + 1769472);         // [3072][768] bf16   4,718,592
    u8*    w_d28  = (u8*)(ws + 6488064);          // [768][3072] fp8    2,359,296
    float* b_qkv  = (float*)(ws + 8847360);       // [2304] f32             9,216
    u16*   xn2    = (u16*)(ws + 8856576);         // [T][768] bf16     25,165,824
    float* x1     = (float*)(ws + 34022400);      // [T][768] f32      50,331,648
    u8*    xn1_8  = (u8*)(ws + 34022400);         // [T][768] fp8 — aliases x1 (dead before attn)
    u8*    qkv8   = (u8*)(ws + 84354048);         // [T][2304] fp8     37,748,736
    u8*    h8     = (u8*)(ws + 84354048);         // [T][3072] fp8 — reuses qkv region (dead after attn)

    cvt_all<<<dim3(2304, 3), 256, 0, stream>>>(
        (const float4*)wq_w, (const float4*)wk_w, (const float4*)wv_w,
        (const float4*)d1_w, (const float4*)d2_w,
        wq_b, wk_b, wv_b,
        (ushort4*)w_d1, (unsigned*)w_d28, (unsigned*)w_qkv8, b_qkv);

    ln_rows_f8<<<T / 4, 256, 0, stream>>>(x, xn1_8, g1, b1);
    gemm_f8<0, 2304, 768><<<dim3(T / 128, 18), 256, 0, stream>>>(xn1_8, w_qkv8, b_qkv, nullptr, qkv8, nullptr);
    attn_ln<<<T / 8, 256, 0, stream>>>(qkv8, x, x1, xn2, g2, b2);
    gemm_up<3072, 768><<<dim3(T / 128, 24), 256, 0, stream>>>(xn2, w_d1, d1_b, h8);
    gemm_f8<2, 768, 3072><<<dim3(T / 128, 6), 256, 0, stream>>>(h8, w_d28, d2_b, x1, nullptr, out);
}

// Round 7
// 368.461 us; speedup vs baseline: 1.0526x; 1.0160x over previous
//
#include <hip/hip_runtime.h>
#include <stdint.h>

#define DIM 768
#define HDIM 3072

typedef unsigned short u16;
typedef unsigned char u8;
typedef unsigned int u32;
typedef __bf16 bf16x8 __attribute__((ext_vector_type(8)));
typedef float f32x2 __attribute__((ext_vector_type(2)));
typedef float f32x4 __attribute__((ext_vector_type(4)));
typedef float f32x16 __attribute__((ext_vector_type(16)));
typedef int i32x8 __attribute__((ext_vector_type(8)));

__device__ __forceinline__ u16 f2b(float f) {
    union { float f; unsigned i; } v; v.f = f;
    unsigned r = (v.i + 0x7FFFu + ((v.i >> 16) & 1u)) >> 16;
    return (u16)r;
}
__device__ __forceinline__ unsigned pack2b(float a, float b) {
    return (unsigned)f2b(a) | ((unsigned)f2b(b) << 16);
}
// tanh-form GELU via v_exp_f32 / v_rcp_f32 (max abs err vs exact ~1e-3)
__device__ __forceinline__ float gelu_f(float v) {
    float u = v * (1.5957691216f + 0.07135481627f * v * v);
    float e = __builtin_amdgcn_exp2f(-1.442695041f * u);
    return v * __builtin_amdgcn_rcpf(1.0f + e);
}
__device__ __forceinline__ void gl_lds16(const void* g, void* l) {
    __builtin_amdgcn_global_load_lds(
        (__attribute__((address_space(1))) void*)(g),
        (__attribute__((address_space(3))) void*)(l), 16, 0, 0);
}

// ---------- merged weight-convert + bias-pack (one launch) ----------
// y=0: d1_w f32->bf16 (589824 f4);  y=1: d2_w f32->fp8 (589824 f4);
// y=2: wq/wk/wv f32->fp8 (3x147456 f4) + qkv bias pack (576 f4-slots).
__global__ __launch_bounds__(256) void cvt_all(
    const float4* __restrict__ wq, const float4* __restrict__ wk, const float4* __restrict__ wv,
    const float4* __restrict__ d1, const float4* __restrict__ d2,
    const float* __restrict__ bq, const float* __restrict__ bk, const float* __restrict__ bv,
    ushort4* __restrict__ o_d1, unsigned* __restrict__ o_d2,
    unsigned* __restrict__ o_qkv, float* __restrict__ o_bias) {
    const int i = blockIdx.x * 256 + threadIdx.x;
    const int y = blockIdx.y;
    if (y == 0) {
        float4 v = d1[i];
        ushort4 o;
        o.x = f2b(v.x); o.y = f2b(v.y); o.z = f2b(v.z); o.w = f2b(v.w);
        o_d1[i] = o;
    } else if (y == 1) {
        float4 v = d2[i];
        int p = __builtin_amdgcn_cvt_pk_fp8_f32(v.x, v.y, 0, false);
        p = __builtin_amdgcn_cvt_pk_fp8_f32(v.z, v.w, p, true);
        o_d2[i] = (unsigned)p;
    } else {
        if (i < 442368) {
            float4 v = (i < 147456) ? wq[i] : (i < 294912 ? wk[i - 147456] : wv[i - 294912]);
            int p = __builtin_amdgcn_cvt_pk_fp8_f32(v.x, v.y, 0, false);
            p = __builtin_amdgcn_cvt_pk_fp8_f32(v.z, v.w, p, true);
            o_qkv[i] = (unsigned)p;
        } else if (i < 442944) {
            const int j = (i - 442368) * 4;
#pragma unroll
            for (int e = 0; e < 4; ++e) {
                int f = j + e;
                float v = (f < 768) ? bq[f] : (f < 1536 ? bk[f - 768] : bv[f - 1536]);
                o_bias[f] = v;
            }
        }
    }
}

// ---------- LayerNorm (ddof=1, eps on std), wave per row, fp8 output ----------
__global__ __launch_bounds__(256) void ln_rows_f8(const float* __restrict__ x, u8* __restrict__ xn,
                                                  const float* __restrict__ g, const float* __restrict__ b) {
    int row = blockIdx.x * 4 + (threadIdx.x >> 6);
    int lane = threadIdx.x & 63;
    const float* xr = x + (size_t)row * DIM + lane * 12;
    float v[12];
#pragma unroll
    for (int i = 0; i < 3; ++i) {
        float4 t = ((const float4*)xr)[i];
        v[i * 4 + 0] = t.x; v[i * 4 + 1] = t.y; v[i * 4 + 2] = t.z; v[i * 4 + 3] = t.w;
    }
    float s = 0.f, ss = 0.f;
#pragma unroll
    for (int i = 0; i < 12; ++i) { s += v[i]; ss += v[i] * v[i]; }
#pragma unroll
    for (int o = 32; o; o >>= 1) { s += __shfl_xor(s, o); ss += __shfl_xor(ss, o); }
    float mean = s * (1.f / DIM);
    float var = (ss - (float)DIM * mean * mean) * (1.f / (DIM - 1));
    float denom = sqrtf(var) + 1e-6f;
    float sc = g[0] / denom, bb = b[0] - mean * sc;
    unsigned* outp = (unsigned*)(xn + (size_t)row * DIM + lane * 12);
#pragma unroll
    for (int i = 0; i < 3; ++i) {
        int p = __builtin_amdgcn_cvt_pk_fp8_f32(v[i * 4 + 0] * sc + bb, v[i * 4 + 1] * sc + bb, 0, false);
        p = __builtin_amdgcn_cvt_pk_fp8_f32(v[i * 4 + 2] * sc + bb, v[i * 4 + 3] * sc + bb, p, true);
        outp[i] = (unsigned)p;
    }
}

// ---------- fp8 GEMM: C[M,N] = A[M,K] @ B[N,K]^T, MX MFMA w/ unit scales ----------
// BK=128, 128x128 tile, swapped mfma(B,A) -> C^T reg layout; coalesced stores
// via LDS-staged, 4B-XOR-swizzled C tile.
// EPI 0: acc+bias -> fp8 out       (QKV)
// EPI 2: acc+bias+resid -> f32 out (MLP down + residual), 2-pass 32KB staging
template <int EPI, int N, int K>
__global__ __launch_bounds__(256)
void gemm_f8(const u8* __restrict__ A, const u8* __restrict__ B,
             const float* __restrict__ bias, const float* __restrict__ resid,
             u8* __restrict__ Co, float* __restrict__ Cf) {
    __shared__ __align__(16) u8 smem[32768];
    u8* As = smem;
    u8* Bs = smem + 16384;
    const int tid = threadIdx.x, lane = tid & 63, wave = tid >> 6;
    const int row0 = blockIdx.x * 128, col0 = blockIdx.y * 128;
    const int wm = (wave >> 1) * 64, wn = (wave & 1) * 64;
    f32x16 acc[2][2] = {};

    const int srow = lane >> 3;
    const int schunk = ((lane & 7) ^ srow) * 16;
    const u8* Ag = A + (size_t)(row0 + wave * 8 + srow) * K + schunk;
    const u8* Bg = B + (size_t)(col0 + wave * 8 + srow) * K + schunk;
    const size_t s32 = (size_t)32 * K;
    u8* AsW = As + wave * 1024;
    u8* BsW = Bs + wave * 1024;

    const int r31 = lane & 31, khalf = lane >> 5;

    for (int kb = 0; kb < K; kb += 128) {
#pragma unroll
        for (int i = 0; i < 4; ++i) {
            gl_lds16(Ag + i * s32, AsW + i * 4096);
            gl_lds16(Bg + i * s32, BsW + i * 4096);
        }
        Ag += 128; Bg += 128;
        __syncthreads();
#pragma unroll
        for (int ks = 0; ks < 2; ++ks) {
            const int c0 = ks * 4 + khalf * 2;
            union { i32x8 v; uint4 q[2]; } af[2], bfr[2];
#pragma unroll
            for (int ib = 0; ib < 2; ++ib) {
                const int r = wm + ib * 32 + r31;
                const u8* base = As + r * 128;
                const int x7 = (r & 7);
                af[ib].q[0] = *(const uint4*)(base + ((c0 ^ x7) * 16));
                af[ib].q[1] = *(const uint4*)(base + (((c0 + 1) ^ x7) * 16));
            }
#pragma unroll
            for (int jb = 0; jb < 2; ++jb) {
                const int r = wn + jb * 32 + r31;
                const u8* base = Bs + r * 128;
                const int x7 = (r & 7);
                bfr[jb].q[0] = *(const uint4*)(base + ((c0 ^ x7) * 16));
                bfr[jb].q[1] = *(const uint4*)(base + (((c0 + 1) ^ x7) * 16));
            }
#pragma unroll
            for (int ib = 0; ib < 2; ++ib)
#pragma unroll
                for (int jb = 0; jb < 2; ++jb)
                    acc[ib][jb] = __builtin_amdgcn_mfma_scale_f32_32x32x64_f8f6f4(
                        bfr[jb].v, af[ib].v, acc[ib][jb], 0, 0,
                        0, 0x7F7F7F7F, 0, 0x7F7F7F7F);
        }
        __syncthreads();
    }
    // C^T frag: local row = wm+ib*32+r31, local col = wn+jb*32+gq*8+4*khalf+(reg&3)
    if (EPI == 0) {
        // stage packed fp8 tile (128 rows x 128B), dword-XOR swizzle
        u32* Cs = (u32*)smem;
#pragma unroll
        for (int ib = 0; ib < 2; ++ib) {
            const int row = wm + ib * 32 + r31;
            const int rx = row & 31;
#pragma unroll
            for (int jb = 0; jb < 2; ++jb)
#pragma unroll
                for (int gq = 0; gq < 4; ++gq) {
                    const int cb = wn + jb * 32 + gq * 8 + 4 * khalf;
                    float4 bv = *(const float4*)(bias + col0 + cb);
                    float v0 = acc[ib][jb][gq * 4 + 0] + bv.x;
                    float v1 = acc[ib][jb][gq * 4 + 1] + bv.y;
                    float v2 = acc[ib][jb][gq * 4 + 2] + bv.z;
                    float v3 = acc[ib][jb][gq * 4 + 3] + bv.w;
                    int p = __builtin_amdgcn_cvt_pk_fp8_f32(v0, v1, 0, false);
                    p = __builtin_amdgcn_cvt_pk_fp8_f32(v2, v3, p, true);
                    Cs[row * 32 + ((cb >> 2) ^ rx)] = (u32)p;
                }
        }
        __syncthreads();
#pragma unroll
        for (int pr = 0; pr < 4; ++pr) {
            const int r = pr * 32 + (tid >> 3);
            const int rx = r & 31;
            const int dwb = (tid & 7) * 4;
            uint4 o;
            o.x = Cs[r * 32 + ((dwb + 0) ^ rx)];
            o.y = Cs[r * 32 + ((dwb + 1) ^ rx)];
            o.z = Cs[r * 32 + ((dwb + 2) ^ rx)];
            o.w = Cs[r * 32 + ((dwb + 3) ^ rx)];
            *(uint4*)(Co + (size_t)(row0 + r) * N + col0 + dwb * 4) = o;
        }
    } else {
        // fp32 out + resid: 2-pass staging, 64 rows x 128 f32 (32KB), 16B-chunk swizzle
        float* Cs = (float*)smem;
#pragma unroll
        for (int pass = 0; pass < 2; ++pass) {
            const int ss = (wm >> 1) + r31;  // slot row 0..63
            const int sx = ss & 7;
#pragma unroll
            for (int jb = 0; jb < 2; ++jb)
#pragma unroll
                for (int gq = 0; gq < 4; ++gq) {
                    const int cb = wn + jb * 32 + gq * 8 + 4 * khalf;
                    float4 bv = *(const float4*)(bias + col0 + cb);
                    float4 v;
                    v.x = acc[pass][jb][gq * 4 + 0] + bv.x;
                    v.y = acc[pass][jb][gq * 4 + 1] + bv.y;
                    v.z = acc[pass][jb][gq * 4 + 2] + bv.z;
                    v.w = acc[pass][jb][gq * 4 + 3] + bv.w;
                    *(float4*)(Cs + ss * 128 + (((cb >> 2) ^ sx) << 2)) = v;
                }
            __syncthreads();
            const int s = tid >> 2;
            const int grow = row0 + (s >> 5) * 64 + pass * 32 + (s & 31);
#pragma unroll
            for (int k = 0; k < 8; ++k) {
                const int c = k * 4 + (tid & 3);
                float4 v = *(const float4*)(Cs + s * 128 + ((c ^ (s & 7)) << 2));
                const size_t gi = (size_t)grow * N + col0 + c * 4;
                float4 rv = *(const float4*)(resid + gi);
                v.x += rv.x; v.y += rv.y; v.z += rv.z; v.w += rv.w;
                *(float4*)(Cf + gi) = v;
            }
            if (pass == 0) __syncthreads();
        }
    }
}

// ---------- bf16 GEMM (MLP up): 32x32x16 MFMA (higher FLOP/cyc, half inst count),
// same BK=64 staging + XOR swizzle as the verified 16x16 version; epilogue copied
// from gemm_f8 EPI0 (shape-determined C/D layout) with gelu+fp8 pack. ----------
template <int N, int K>
__global__ __launch_bounds__(256)
void gemm_up(const u16* __restrict__ A, const u16* __restrict__ B,
             const float* __restrict__ bias, u8* __restrict__ C8) {
    __shared__ __align__(16) u16 As[128 * 64];
    __shared__ __align__(16) u16 Bs[128 * 64];
    const int tid = threadIdx.x;
    const int row0 = blockIdx.x * 128, col0 = blockIdx.y * 128;
    const int lane = tid & 63, wave = tid >> 6;
    const int wm = (wave >> 1) * 64, wn = (wave & 1) * 64;
    const int r31 = lane & 31, khalf = lane >> 5;
    f32x16 acc[2][2] = {};

    const int srow = lane >> 3;
    const int schunk = (lane & 7) ^ srow;
    const u16* Ag = A + (size_t)(row0 + wave * 8 + srow) * K + schunk * 8;
    const u16* Bg = B + (size_t)(col0 + wave * 8 + srow) * K + schunk * 8;
    const size_t s32 = (size_t)32 * K;
    u16* AsW = &As[wave * 512];
    u16* BsW = &Bs[wave * 512];

    // row&7 is identical for ib=0/1 (rows differ by 32): one XOR per operand set
    const int xr = r31 & 7;
    const u16* a0base = &As[(wm + r31) * 64];
    const u16* a1base = &As[(wm + 32 + r31) * 64];
    const u16* b0base = &Bs[(wn + r31) * 64];
    const u16* b1base = &Bs[(wn + 32 + r31) * 64];

    for (int kb = 0; kb < K; kb += 64) {
#pragma unroll
        for (int i = 0; i < 4; ++i) {
            gl_lds16(Ag + i * s32, AsW + i * 2048);
            gl_lds16(Bg + i * s32, BsW + i * 2048);
        }
        Ag += 64; Bg += 64;
        __syncthreads();
        // 4 K-steps of 16; lane holds 8 bf16 at k = ks*16 + khalf*8 (chunk ks*2+khalf)
#pragma unroll
        for (int ks = 0; ks < 4; ++ks) {
            const int cp = ((ks * 2 + khalf) ^ xr) * 8;
            bf16x8 af0 = *(const bf16x8*)(a0base + cp);
            bf16x8 af1 = *(const bf16x8*)(a1base + cp);
            bf16x8 bf0 = *(const bf16x8*)(b0base + cp);
            bf16x8 bf1 = *(const bf16x8*)(b1base + cp);
            acc[0][0] = __builtin_amdgcn_mfma_f32_32x32x16_bf16(bf0, af0, acc[0][0], 0, 0, 0);
            acc[0][1] = __builtin_amdgcn_mfma_f32_32x32x16_bf16(bf1, af0, acc[0][1], 0, 0, 0);
            acc[1][0] = __builtin_amdgcn_mfma_f32_32x32x16_bf16(bf0, af1, acc[1][0], 0, 0, 0);
            acc[1][1] = __builtin_amdgcn_mfma_f32_32x32x16_bf16(bf1, af1, acc[1][1], 0, 0, 0);
        }
        __syncthreads();
    }
    // C^T frag (32x32 shape): local row = wm+ib*32+r31,
    // local col = wn+jb*32+gq*8+4*khalf+(reg&3)  [same map as gemm_f8 EPI0]
    u32* Cs = (u32*)As;  // 16KB fp8 tile stage
#pragma unroll
    for (int ib = 0; ib < 2; ++ib) {
        const int row = wm + ib * 32 + r31;
        const int rx = row & 31;
#pragma unroll
        for (int jb = 0; jb < 2; ++jb)
#pragma unroll
            for (int gq = 0; gq < 4; ++gq) {
                const int cb = wn + jb * 32 + gq * 8 + 4 * khalf;
                float4 bv = *(const float4*)(bias + col0 + cb);
                float v0 = gelu_f(acc[ib][jb][gq * 4 + 0] + bv.x);
                float v1 = gelu_f(acc[ib][jb][gq * 4 + 1] + bv.y);
                float v2 = gelu_f(acc[ib][jb][gq * 4 + 2] + bv.z);
                float v3 = gelu_f(acc[ib][jb][gq * 4 + 3] + bv.w);
                int p = __builtin_amdgcn_cvt_pk_fp8_f32(v0, v1, 0, false);
                p = __builtin_amdgcn_cvt_pk_fp8_f32(v2, v3, p, true);
                Cs[row * 32 + ((cb >> 2) ^ rx)] = (u32)p;
            }
    }
    __syncthreads();
#pragma unroll
    for (int pr = 0; pr < 4; ++pr) {
        const int r = pr * 32 + (tid >> 3);
        const int rx = r & 31;
        const int dwb = (tid & 7) * 4;
        uint4 o;
        o.x = Cs[r * 32 + ((dwb + 0) ^ rx)];
        o.y = Cs[r * 32 + ((dwb + 1) ^ rx)];
        o.z = Cs[r * 32 + ((dwb + 2) ^ rx)];
        o.w = Cs[r * 32 + ((dwb + 3) ^ rx)];
        *(uint4*)(C8 + (size_t)(row0 + r) * N + col0 + dwb * 4) = o;
    }
}

// ---------- attention (8-token groups, fp8 qkv) + residual + LN2 ----------
__global__ __launch_bounds__(256)
void attn_ln(const u8* __restrict__ qkv, const float* __restrict__ x,
             float* __restrict__ x1, u16* __restrict__ xn2,
             const float* __restrict__ g, const float* __restrict__ b) {
    __shared__ __align__(16) u8 sq[8 * 2304];
    __shared__ float sw[64];
    const int tid = threadIdx.x;
    const uint4* src = (const uint4*)(qkv + (size_t)blockIdx.x * (8 * 2304));
    uint4* dst = (uint4*)sq;
#pragma unroll
    for (int i = 0; i < 5; ++i) {
        int idx = tid + i * 256;
        if (idx < 1152) dst[idx] = src[idx];
    }
    __syncthreads();
    const u32* sq32 = (const u32*)sq;
    const int wave = tid >> 6, lane = tid & 63;
#pragma unroll 2
    for (int p = wave * 16; p < wave * 16 + 16; ++p) {
        const u32* qr = sq32 + (p >> 3) * 576 + lane * 3;
        const u32* kr = sq32 + (p & 7) * 576 + 192 + lane * 3;
        float s = 0.f;
#pragma unroll
        for (int i = 0; i < 3; ++i) {
            u32 qd = qr[i], kd = kr[i];
            f32x2 q0 = __builtin_amdgcn_cvt_pk_f32_fp8(qd, false);
            f32x2 q1 = __builtin_amdgcn_cvt_pk_f32_fp8(qd, true);
            f32x2 k0 = __builtin_amdgcn_cvt_pk_f32_fp8(kd, false);
            f32x2 k1 = __builtin_amdgcn_cvt_pk_f32_fp8(kd, true);
            s += q0[0] * k0[0] + q0[1] * k0[1] + q1[0] * k1[0] + q1[1] * k1[1];
        }
#pragma unroll
        for (int o = 32; o; o >>= 1) s += __shfl_xor(s, o);
        if (lane == 0) sw[p] = s;
    }
    __syncthreads();
    if (tid < 8) {
        const float scl = 0.03608439182435161f; // 1/sqrt(768)
        float e[8]; float m = -1e30f;
#pragma unroll
        for (int j = 0; j < 8; ++j) m = fmaxf(m, sw[tid * 8 + j]);
        float sum = 0.f;
#pragma unroll
        for (int j = 0; j < 8; ++j) { e[j] = expf((sw[tid * 8 + j] - m) * scl); sum += e[j]; }
        float inv = 1.f / sum;
#pragma unroll
        for (int j = 0; j < 8; ++j) sw[tid * 8 + j] = e[j] * inv;
    }
    __syncthreads();
    const int h = tid >> 5, li = tid & 31;
    float w[8];
#pragma unroll
    for (int kk = 0; kk < 8; ++kk) w[kk] = sw[h * 8 + kk];
    const size_t trow = (size_t)blockIdx.x * 8 + h;
    const float* xr = x + trow * DIM;
    float* x1r = x1 + trow * DIM;
    float xv[24], s = 0.f, ss = 0.f;
#pragma unroll
    for (int wd = 0; wd < 3; ++wd) {
        const int d0 = wd * 256 + li * 8;
        float o[8] = {};
#pragma unroll
        for (int kk = 0; kk < 8; ++kk) {
            uint2 vv = *(const uint2*)(sq32 + kk * 576 + 384 + wd * 64 + li * 2);
            f32x2 a0 = __builtin_amdgcn_cvt_pk_f32_fp8(vv.x, false);
            f32x2 a1 = __builtin_amdgcn_cvt_pk_f32_fp8(vv.x, true);
            f32x2 a2 = __builtin_amdgcn_cvt_pk_f32_fp8(vv.y, false);
            f32x2 a3 = __builtin_amdgcn_cvt_pk_f32_fp8(vv.y, true);
            o[0] += w[kk] * a0[0]; o[1] += w[kk] * a0[1];
            o[2] += w[kk] * a1[0]; o[3] += w[kk] * a1[1];
            o[4] += w[kk] * a2[0]; o[5] += w[kk] * a2[1];
            o[6] += w[kk] * a3[0]; o[7] += w[kk] * a3[1];
        }
        float4 xa = *(const float4*)(xr + d0);
        float4 xb = *(const float4*)(xr + d0 + 4);
        float vals[8] = { o[0] + xa.x, o[1] + xa.y, o[2] + xa.z, o[3] + xa.w,
                          o[4] + xb.x, o[5] + xb.y, o[6] + xb.z, o[7] + xb.w };
        float4 w0, w1;
        w0.x = vals[0]; w0.y = vals[1]; w0.z = vals[2]; w0.w = vals[3];
        w1.x = vals[4]; w1.y = vals[5]; w1.z = vals[6]; w1.w = vals[7];
        *(float4*)(x1r + d0) = w0;
        *(float4*)(x1r + d0 + 4) = w1;
#pragma unroll
        for (int e = 0; e < 8; ++e) {
            xv[wd * 8 + e] = vals[e];
            s += vals[e]; ss += vals[e] * vals[e];
        }
    }
#pragma unroll
    for (int o2 = 16; o2; o2 >>= 1) { s += __shfl_xor(s, o2); ss += __shfl_xor(ss, o2); }
    float mean = s * (1.f / 768.f);
    float var = (ss - 768.f * mean * mean) * (1.f / 767.f);
    float denom = sqrtf(var) + 1e-6f;
    float sc = g[0] / denom, bb = b[0] - mean * sc;
    u16* xnr = xn2 + trow * DIM;
#pragma unroll
    for (int wd = 0; wd < 3; ++wd) {
        const int d0 = wd * 256 + li * 8;
        uint4 o;
        o.x = pack2b(xv[wd * 8 + 0] * sc + bb, xv[wd * 8 + 1] * sc + bb);
        o.y = pack2b(xv[wd * 8 + 2] * sc + bb, xv[wd * 8 + 3] * sc + bb);
        o.z = pack2b(xv[wd * 8 + 4] * sc + bb, xv[wd * 8 + 5] * sc + bb);
        o.w = pack2b(xv[wd * 8 + 6] * sc + bb, xv[wd * 8 + 7] * sc + bb);
        *(uint4*)(xnr + d0) = o;
    }
}

extern "C" void kernel_launch(void* const* d_in, const int* in_sizes, int n_in,
                              void* d_out, int out_size, void* d_ws, size_t ws_size,
                              hipStream_t stream) {
    (void)n_in; (void)out_size; (void)ws_size;
    const float* x    = (const float*)d_in[0];
    const float* wq_w = (const float*)d_in[1];
    const float* wq_b = (const float*)d_in[2];
    const float* wk_w = (const float*)d_in[3];
    const float* wk_b = (const float*)d_in[4];
    const float* wv_w = (const float*)d_in[5];
    const float* wv_b = (const float*)d_in[6];
    const float* d1_w = (const float*)d_in[7];
    const float* d1_b = (const float*)d_in[8];
    const float* d2_w = (const float*)d_in[9];
    const float* d2_b = (const float*)d_in[10];
    const float* g1 = (const float*)d_in[11];
    const float* b1 = (const float*)d_in[12];
    const float* g2 = (const float*)d_in[13];
    const float* b2 = (const float*)d_in[14];
    float* out = (float*)d_out;
    char* ws = (char*)d_ws;

    const int T = in_sizes[0] / DIM;  // 16384

    // ws layout (bytes):
    u8*    w_qkv8 = (u8*)(ws);                    // [2304][768] fp8    1,769,472
    u16*   w_d1   = (u16*)(ws + 1769472);         // [3072][768] bf16   4,718,592
    u8*    w_d28  = (u8*)(ws + 6488064);          // [768][3072] fp8    2,359,296
    float* b_qkv  = (float*)(ws + 8847360);       // [2304] f32             9,216
    u16*   xn2    = (u16*)(ws + 8856576);         // [T][768] bf16     25,165,824
    float* x1     = (float*)(ws + 34022400);      // [T][768] f32      50,331,648
    u8*    xn1_8  = (u8*)(ws + 34022400);         // [T][768] fp8 — aliases x1 (dead before attn)
    u8*    qkv8   = (u8*)(ws + 84354048);         // [T][2304] fp8     37,748,736
    u8*    h8     = (u8*)(ws + 84354048);         // [T][3072] fp8 — reuses qkv region (dead after attn)

    cvt_all<<<dim3(2304, 3), 256, 0, stream>>>(
        (const float4*)wq_w, (const float4*)wk_w, (const float4*)wv_w,
        (const float4*)d1_w, (const float4*)d2_w,
        wq_b, wk_b, wv_b,
        (ushort4*)w_d1, (unsigned*)w_d28, (unsigned*)w_qkv8, b_qkv);

    ln_rows_f8<<<T / 4, 256, 0, stream>>>(x, xn1_8, g1, b1);
    gemm_f8<0, 2304, 768><<<dim3(T / 128, 18), 256, 0, stream>>>(xn1_8, w_qkv8, b_qkv, nullptr, qkv8, nullptr);
    attn_ln<<<T / 8, 256, 0, stream>>>(qkv8, x, x1, xn2, g2, b2);
    gemm_up<3072, 768><<<dim3(T / 128, 24), 256, 0, stream>>>(xn2, w_d1, d1_b, h8);
    gemm_f8<2, 768, 3072><<<dim3(T / 128, 6), 256, 0, stream>>>(h8, w_d28, d2_b, x1, nullptr, out);
}

// Round 8
// 353.485 us; speedup vs baseline: 1.0972x; 1.0424x over previous
//
#include <hip/hip_runtime.h>
#include <stdint.h>

#define DIM 768
#define HDIM 3072

typedef unsigned short u16;
typedef unsigned char u8;
typedef unsigned int u32;
typedef __bf16 bf16x8 __attribute__((ext_vector_type(8)));
typedef float f32x2 __attribute__((ext_vector_type(2)));
typedef float f32x4 __attribute__((ext_vector_type(4)));
typedef float f32x16 __attribute__((ext_vector_type(16)));
typedef int i32x8 __attribute__((ext_vector_type(8)));

__device__ __forceinline__ u16 f2b(float f) {
    union { float f; unsigned i; } v; v.f = f;
    unsigned r = (v.i + 0x7FFFu + ((v.i >> 16) & 1u)) >> 16;
    return (u16)r;
}
__device__ __forceinline__ unsigned pack2b(float a, float b) {
    return (unsigned)f2b(a) | ((unsigned)f2b(b) << 16);
}
// tanh-form GELU via v_exp_f32 / v_rcp_f32 (max abs err vs exact ~1e-3)
__device__ __forceinline__ float gelu_f(float v) {
    float u = v * (1.5957691216f + 0.07135481627f * v * v);
    float e = __builtin_amdgcn_exp2f(-1.442695041f * u);
    return v * __builtin_amdgcn_rcpf(1.0f + e);
}
__device__ __forceinline__ void gl_lds16(const void* g, void* l) {
    __builtin_amdgcn_global_load_lds(
        (__attribute__((address_space(1))) void*)(g),
        (__attribute__((address_space(3))) void*)(l), 16, 0, 0);
}

// ---------- merged weight-convert + bias-pack (one launch) ----------
// Weights are pre-scaled by 32 (2^5) before fp8 e4m3 conversion to lift
// N(0,0.02) values out of e4m3's denormal range (min normal 2^-6 = 0.0156,
// where rel-err reaches ~20%). The MX MFMA applies 2^-5 via scale byte 0x7A.
// y=0: d1_w f32->bf16 (589824 f4);  y=1: d2_w f32->fp8*32 (589824 f4);
// y=2: wq/wk/wv f32->fp8*32 (3x147456 f4) + qkv bias pack (576 f4-slots).
__global__ __launch_bounds__(256) void cvt_all(
    const float4* __restrict__ wq, const float4* __restrict__ wk, const float4* __restrict__ wv,
    const float4* __restrict__ d1, const float4* __restrict__ d2,
    const float* __restrict__ bq, const float* __restrict__ bk, const float* __restrict__ bv,
    ushort4* __restrict__ o_d1, unsigned* __restrict__ o_d2,
    unsigned* __restrict__ o_qkv, float* __restrict__ o_bias) {
    const int i = blockIdx.x * 256 + threadIdx.x;
    const int y = blockIdx.y;
    if (y == 0) {
        float4 v = d1[i];
        ushort4 o;
        o.x = f2b(v.x); o.y = f2b(v.y); o.z = f2b(v.z); o.w = f2b(v.w);
        o_d1[i] = o;
    } else if (y == 1) {
        float4 v = d2[i];
        int p = __builtin_amdgcn_cvt_pk_fp8_f32(v.x * 32.f, v.y * 32.f, 0, false);
        p = __builtin_amdgcn_cvt_pk_fp8_f32(v.z * 32.f, v.w * 32.f, p, true);
        o_d2[i] = (unsigned)p;
    } else {
        if (i < 442368) {
            float4 v = (i < 147456) ? wq[i] : (i < 294912 ? wk[i - 147456] : wv[i - 294912]);
            int p = __builtin_amdgcn_cvt_pk_fp8_f32(v.x * 32.f, v.y * 32.f, 0, false);
            p = __builtin_amdgcn_cvt_pk_fp8_f32(v.z * 32.f, v.w * 32.f, p, true);
            o_qkv[i] = (unsigned)p;
        } else if (i < 442944) {
            const int j = (i - 442368) * 4;
#pragma unroll
            for (int e = 0; e < 4; ++e) {
                int f = j + e;
                float v = (f < 768) ? bq[f] : (f < 1536 ? bk[f - 768] : bv[f - 1536]);
                o_bias[f] = v;
            }
        }
    }
}

// ---------- LayerNorm (ddof=1, eps on std), wave per row, fp8 output ----------
__global__ __launch_bounds__(256) void ln_rows_f8(const float* __restrict__ x, u8* __restrict__ xn,
                                                  const float* __restrict__ g, const float* __restrict__ b) {
    int row = blockIdx.x * 4 + (threadIdx.x >> 6);
    int lane = threadIdx.x & 63;
    const float* xr = x + (size_t)row * DIM + lane * 12;
    float v[12];
#pragma unroll
    for (int i = 0; i < 3; ++i) {
        float4 t = ((const float4*)xr)[i];
        v[i * 4 + 0] = t.x; v[i * 4 + 1] = t.y; v[i * 4 + 2] = t.z; v[i * 4 + 3] = t.w;
    }
    float s = 0.f, ss = 0.f;
#pragma unroll
    for (int i = 0; i < 12; ++i) { s += v[i]; ss += v[i] * v[i]; }
#pragma unroll
    for (int o = 32; o; o >>= 1) { s += __shfl_xor(s, o); ss += __shfl_xor(ss, o); }
    float mean = s * (1.f / DIM);
    float var = (ss - (float)DIM * mean * mean) * (1.f / (DIM - 1));
    float denom = sqrtf(var) + 1e-6f;
    float sc = g[0] / denom, bb = b[0] - mean * sc;
    unsigned* outp = (unsigned*)(xn + (size_t)row * DIM + lane * 12);
#pragma unroll
    for (int i = 0; i < 3; ++i) {
        int p = __builtin_amdgcn_cvt_pk_fp8_f32(v[i * 4 + 0] * sc + bb, v[i * 4 + 1] * sc + bb, 0, false);
        p = __builtin_amdgcn_cvt_pk_fp8_f32(v[i * 4 + 2] * sc + bb, v[i * 4 + 3] * sc + bb, p, true);
        outp[i] = (unsigned)p;
    }
}

// ---------- fp8 GEMM: C[M,N] = A[M,K] @ B[N,K]^T, MX MFMA ----------
// B (weights) pre-scaled by 2^5 at convert; HW applies 2^-5 via scale 0x7A7A7A7A.
// A (activations) unit scale 0x7F7F7F7F.
// BK=128, 128x128 tile, swapped mfma(B,A) -> C^T reg layout; coalesced stores
// via LDS-staged, 4B-XOR-swizzled C tile.
// EPI 0: acc+bias -> fp8 out       (QKV)
// EPI 2: acc+bias+resid -> f32 out (MLP down + residual), 2-pass 32KB staging
template <int EPI, int N, int K>
__global__ __launch_bounds__(256)
void gemm_f8(const u8* __restrict__ A, const u8* __restrict__ B,
             const float* __restrict__ bias, const float* __restrict__ resid,
             u8* __restrict__ Co, float* __restrict__ Cf) {
    __shared__ __align__(16) u8 smem[32768];
    u8* As = smem;
    u8* Bs = smem + 16384;
    const int tid = threadIdx.x, lane = tid & 63, wave = tid >> 6;
    const int row0 = blockIdx.x * 128, col0 = blockIdx.y * 128;
    const int wm = (wave >> 1) * 64, wn = (wave & 1) * 64;
    f32x16 acc[2][2] = {};

    const int srow = lane >> 3;
    const int schunk = ((lane & 7) ^ srow) * 16;
    const u8* Ag = A + (size_t)(row0 + wave * 8 + srow) * K + schunk;
    const u8* Bg = B + (size_t)(col0 + wave * 8 + srow) * K + schunk;
    const size_t s32 = (size_t)32 * K;
    u8* AsW = As + wave * 1024;
    u8* BsW = Bs + wave * 1024;

    const int r31 = lane & 31, khalf = lane >> 5;

    for (int kb = 0; kb < K; kb += 128) {
#pragma unroll
        for (int i = 0; i < 4; ++i) {
            gl_lds16(Ag + i * s32, AsW + i * 4096);
            gl_lds16(Bg + i * s32, BsW + i * 4096);
        }
        Ag += 128; Bg += 128;
        __syncthreads();
#pragma unroll
        for (int ks = 0; ks < 2; ++ks) {
            const int c0 = ks * 4 + khalf * 2;
            union { i32x8 v; uint4 q[2]; } af[2], bfr[2];
#pragma unroll
            for (int ib = 0; ib < 2; ++ib) {
                const int r = wm + ib * 32 + r31;
                const u8* base = As + r * 128;
                const int x7 = (r & 7);
                af[ib].q[0] = *(const uint4*)(base + ((c0 ^ x7) * 16));
                af[ib].q[1] = *(const uint4*)(base + (((c0 + 1) ^ x7) * 16));
            }
#pragma unroll
            for (int jb = 0; jb < 2; ++jb) {
                const int r = wn + jb * 32 + r31;
                const u8* base = Bs + r * 128;
                const int x7 = (r & 7);
                bfr[jb].q[0] = *(const uint4*)(base + ((c0 ^ x7) * 16));
                bfr[jb].q[1] = *(const uint4*)(base + (((c0 + 1) ^ x7) * 16));
            }
#pragma unroll
            for (int ib = 0; ib < 2; ++ib)
#pragma unroll
                for (int jb = 0; jb < 2; ++jb)
                    acc[ib][jb] = __builtin_amdgcn_mfma_scale_f32_32x32x64_f8f6f4(
                        bfr[jb].v, af[ib].v, acc[ib][jb], 0, 0,
                        0, 0x7A7A7A7A,   // weights operand: 2^-5 (undo 32x prescale)
                        0, 0x7F7F7F7F);  // activations: unit
        }
        __syncthreads();
    }
    // C^T frag: local row = wm+ib*32+r31, local col = wn+jb*32+gq*8+4*khalf+(reg&3)
    if (EPI == 0) {
        // stage packed fp8 tile (128 rows x 128B), dword-XOR swizzle
        u32* Cs = (u32*)smem;
#pragma unroll
        for (int ib = 0; ib < 2; ++ib) {
            const int row = wm + ib * 32 + r31;
            const int rx = row & 31;
#pragma unroll
            for (int jb = 0; jb < 2; ++jb)
#pragma unroll
                for (int gq = 0; gq < 4; ++gq) {
                    const int cb = wn + jb * 32 + gq * 8 + 4 * khalf;
                    float4 bv = *(const float4*)(bias + col0 + cb);
                    float v0 = acc[ib][jb][gq * 4 + 0] + bv.x;
                    float v1 = acc[ib][jb][gq * 4 + 1] + bv.y;
                    float v2 = acc[ib][jb][gq * 4 + 2] + bv.z;
                    float v3 = acc[ib][jb][gq * 4 + 3] + bv.w;
                    int p = __builtin_amdgcn_cvt_pk_fp8_f32(v0, v1, 0, false);
                    p = __builtin_amdgcn_cvt_pk_fp8_f32(v2, v3, p, true);
                    Cs[row * 32 + ((cb >> 2) ^ rx)] = (u32)p;
                }
        }
        __syncthreads();
#pragma unroll
        for (int pr = 0; pr < 4; ++pr) {
            const int r = pr * 32 + (tid >> 3);
            const int rx = r & 31;
            const int dwb = (tid & 7) * 4;
            uint4 o;
            o.x = Cs[r * 32 + ((dwb + 0) ^ rx)];
            o.y = Cs[r * 32 + ((dwb + 1) ^ rx)];
            o.z = Cs[r * 32 + ((dwb + 2) ^ rx)];
            o.w = Cs[r * 32 + ((dwb + 3) ^ rx)];
            *(uint4*)(Co + (size_t)(row0 + r) * N + col0 + dwb * 4) = o;
        }
    } else {
        // fp32 out + resid: 2-pass staging, 64 rows x 128 f32 (32KB), 16B-chunk swizzle
        float* Cs = (float*)smem;
#pragma unroll
        for (int pass = 0; pass < 2; ++pass) {
            const int ss = (wm >> 1) + r31;  // slot row 0..63
            const int sx = ss & 7;
#pragma unroll
            for (int jb = 0; jb < 2; ++jb)
#pragma unroll
                for (int gq = 0; gq < 4; ++gq) {
                    const int cb = wn + jb * 32 + gq * 8 + 4 * khalf;
                    float4 bv = *(const float4*)(bias + col0 + cb);
                    float4 v;
                    v.x = acc[pass][jb][gq * 4 + 0] + bv.x;
                    v.y = acc[pass][jb][gq * 4 + 1] + bv.y;
                    v.z = acc[pass][jb][gq * 4 + 2] + bv.z;
                    v.w = acc[pass][jb][gq * 4 + 3] + bv.w;
                    *(float4*)(Cs + ss * 128 + (((cb >> 2) ^ sx) << 2)) = v;
                }
            __syncthreads();
            const int s = tid >> 2;
            const int grow = row0 + (s >> 5) * 64 + pass * 32 + (s & 31);
#pragma unroll
            for (int k = 0; k < 8; ++k) {
                const int c = k * 4 + (tid & 3);
                float4 v = *(const float4*)(Cs + s * 128 + ((c ^ (s & 7)) << 2));
                const size_t gi = (size_t)grow * N + col0 + c * 4;
                float4 rv = *(const float4*)(resid + gi);
                v.x += rv.x; v.y += rv.y; v.z += rv.z; v.w += rv.w;
                *(float4*)(Cf + gi) = v;
            }
            if (pass == 0) __syncthreads();
        }
    }
}

// ---------- bf16 GEMM (MLP up): 32x32x16 MFMA (higher FLOP/cyc, half inst count),
// same BK=64 staging + XOR swizzle as the verified 16x16 version; epilogue copied
// from gemm_f8 EPI0 (shape-determined C/D layout) with gelu+fp8 pack. ----------
template <int N, int K>
__global__ __launch_bounds__(256)
void gemm_up(const u16* __restrict__ A, const u16* __restrict__ B,
             const float* __restrict__ bias, u8* __restrict__ C8) {
    __shared__ __align__(16) u16 As[128 * 64];
    __shared__ __align__(16) u16 Bs[128 * 64];
    const int tid = threadIdx.x;
    const int row0 = blockIdx.x * 128, col0 = blockIdx.y * 128;
    const int lane = tid & 63, wave = tid >> 6;
    const int wm = (wave >> 1) * 64, wn = (wave & 1) * 64;
    const int r31 = lane & 31, khalf = lane >> 5;
    f32x16 acc[2][2] = {};

    const int srow = lane >> 3;
    const int schunk = (lane & 7) ^ srow;
    const u16* Ag = A + (size_t)(row0 + wave * 8 + srow) * K + schunk * 8;
    const u16* Bg = B + (size_t)(col0 + wave * 8 + srow) * K + schunk * 8;
    const size_t s32 = (size_t)32 * K;
    u16* AsW = &As[wave * 512];
    u16* BsW = &Bs[wave * 512];

    // row&7 is identical for ib=0/1 (rows differ by 32): one XOR per operand set
    const int xr = r31 & 7;
    const u16* a0base = &As[(wm + r31) * 64];
    const u16* a1base = &As[(wm + 32 + r31) * 64];
    const u16* b0base = &Bs[(wn + r31) * 64];
    const u16* b1base = &Bs[(wn + 32 + r31) * 64];

    for (int kb = 0; kb < K; kb += 64) {
#pragma unroll
        for (int i = 0; i < 4; ++i) {
            gl_lds16(Ag + i * s32, AsW + i * 2048);
            gl_lds16(Bg + i * s32, BsW + i * 2048);
        }
        Ag += 64; Bg += 64;
        __syncthreads();
        // 4 K-steps of 16; lane holds 8 bf16 at k = ks*16 + khalf*8 (chunk ks*2+khalf)
#pragma unroll
        for (int ks = 0; ks < 4; ++ks) {
            const int cp = ((ks * 2 + khalf) ^ xr) * 8;
            bf16x8 af0 = *(const bf16x8*)(a0base + cp);
            bf16x8 af1 = *(const bf16x8*)(a1base + cp);
            bf16x8 bf0 = *(const bf16x8*)(b0base + cp);
            bf16x8 bf1 = *(const bf16x8*)(b1base + cp);
            acc[0][0] = __builtin_amdgcn_mfma_f32_32x32x16_bf16(bf0, af0, acc[0][0], 0, 0, 0);
            acc[0][1] = __builtin_amdgcn_mfma_f32_32x32x16_bf16(bf1, af0, acc[0][1], 0, 0, 0);
            acc[1][0] = __builtin_amdgcn_mfma_f32_32x32x16_bf16(bf0, af1, acc[1][0], 0, 0, 0);
            acc[1][1] = __builtin_amdgcn_mfma_f32_32x32x16_bf16(bf1, af1, acc[1][1], 0, 0, 0);
        }
        __syncthreads();
    }
    // C^T frag (32x32 shape): local row = wm+ib*32+r31,
    // local col = wn+jb*32+gq*8+4*khalf+(reg&3)  [same map as gemm_f8 EPI0]
    u32* Cs = (u32*)As;  // 16KB fp8 tile stage
#pragma unroll
    for (int ib = 0; ib < 2; ++ib) {
        const int row = wm + ib * 32 + r31;
        const int rx = row & 31;
#pragma unroll
        for (int jb = 0; jb < 2; ++jb)
#pragma unroll
            for (int gq = 0; gq < 4; ++gq) {
                const int cb = wn + jb * 32 + gq * 8 + 4 * khalf;
                float4 bv = *(const float4*)(bias + col0 + cb);
                float v0 = gelu_f(acc[ib][jb][gq * 4 + 0] + bv.x);
                float v1 = gelu_f(acc[ib][jb][gq * 4 + 1] + bv.y);
                float v2 = gelu_f(acc[ib][jb][gq * 4 + 2] + bv.z);
                float v3 = gelu_f(acc[ib][jb][gq * 4 + 3] + bv.w);
                int p = __builtin_amdgcn_cvt_pk_fp8_f32(v0, v1, 0, false);
                p = __builtin_amdgcn_cvt_pk_fp8_f32(v2, v3, p, true);
                Cs[row * 32 + ((cb >> 2) ^ rx)] = (u32)p;
            }
    }
    __syncthreads();
#pragma unroll
    for (int pr = 0; pr < 4; ++pr) {
        const int r = pr * 32 + (tid >> 3);
        const int rx = r & 31;
        const int dwb = (tid & 7) * 4;
        uint4 o;
        o.x = Cs[r * 32 + ((dwb + 0) ^ rx)];
        o.y = Cs[r * 32 + ((dwb + 1) ^ rx)];
        o.z = Cs[r * 32 + ((dwb + 2) ^ rx)];
        o.w = Cs[r * 32 + ((dwb + 3) ^ rx)];
        *(uint4*)(C8 + (size_t)(row0 + r) * N + col0 + dwb * 4) = o;
    }
}

// ---------- attention (8-token groups, fp8 qkv) + residual + LN2 ----------
__global__ __launch_bounds__(256)
void attn_ln(const u8* __restrict__ qkv, const float* __restrict__ x,
             float* __restrict__ x1, u16* __restrict__ xn2,
             const float* __restrict__ g, const float* __restrict__ b) {
    __shared__ __align__(16) u8 sq[8 * 2304];
    __shared__ float sw[64];
    const int tid = threadIdx.x;
    const uint4* src = (const uint4*)(qkv + (size_t)blockIdx.x * (8 * 2304));
    uint4* dst = (uint4*)sq;
#pragma unroll
    for (int i = 0; i < 5; ++i) {
        int idx = tid + i * 256;
        if (idx < 1152) dst[idx] = src[idx];
    }
    __syncthreads();
    const u32* sq32 = (const u32*)sq;
    const int wave = tid >> 6, lane = tid & 63;
#pragma unroll 2
    for (int p = wave * 16; p < wave * 16 + 16; ++p) {
        const u32* qr = sq32 + (p >> 3) * 576 + lane * 3;
        const u32* kr = sq32 + (p & 7) * 576 + 192 + lane * 3;
        float s = 0.f;
#pragma unroll
        for (int i = 0; i < 3; ++i) {
            u32 qd = qr[i], kd = kr[i];
            f32x2 q0 = __builtin_amdgcn_cvt_pk_f32_fp8(qd, false);
            f32x2 q1 = __builtin_amdgcn_cvt_pk_f32_fp8(qd, true);
            f32x2 k0 = __builtin_amdgcn_cvt_pk_f32_fp8(kd, false);
            f32x2 k1 = __builtin_amdgcn_cvt_pk_f32_fp8(kd, true);
            s += q0[0] * k0[0] + q0[1] * k0[1] + q1[0] * k1[0] + q1[1] * k1[1];
        }
#pragma unroll
        for (int o = 32; o; o >>= 1) s += __shfl_xor(s, o);
        if (lane == 0) sw[p] = s;
    }
    __syncthreads();
    if (tid < 8) {
        const float scl = 0.03608439182435161f; // 1/sqrt(768)
        float e[8]; float m = -1e30f;
#pragma unroll
        for (int j = 0; j < 8; ++j) m = fmaxf(m, sw[tid * 8 + j]);
        float sum = 0.f;
#pragma unroll
        for (int j = 0; j < 8; ++j) { e[j] = expf((sw[tid * 8 + j] - m) * scl); sum += e[j]; }
        float inv = 1.f / sum;
#pragma unroll
        for (int j = 0; j < 8; ++j) sw[tid * 8 + j] = e[j] * inv;
    }
    __syncthreads();
    const int h = tid >> 5, li = tid & 31;
    float w[8];
#pragma unroll
    for (int kk = 0; kk < 8; ++kk) w[kk] = sw[h * 8 + kk];
    const size_t trow = (size_t)blockIdx.x * 8 + h;
    const float* xr = x + trow * DIM;
    float* x1r = x1 + trow * DIM;
    float xv[24], s = 0.f, ss = 0.f;
#pragma unroll
    for (int wd = 0; wd < 3; ++wd) {
        const int d0 = wd * 256 + li * 8;
        float o[8] = {};
#pragma unroll
        for (int kk = 0; kk < 8; ++kk) {
            uint2 vv = *(const uint2*)(sq32 + kk * 576 + 384 + wd * 64 + li * 2);
            f32x2 a0 = __builtin_amdgcn_cvt_pk_f32_fp8(vv.x, false);
            f32x2 a1 = __builtin_amdgcn_cvt_pk_f32_fp8(vv.x, true);
            f32x2 a2 = __builtin_amdgcn_cvt_pk_f32_fp8(vv.y, false);
            f32x2 a3 = __builtin_amdgcn_cvt_pk_f32_fp8(vv.y, true);
            o[0] += w[kk] * a0[0]; o[1] += w[kk] * a0[1];
            o[2] += w[kk] * a1[0]; o[3] += w[kk] * a1[1];
            o[4] += w[kk] * a2[0]; o[5] += w[kk] * a2[1];
            o[6] += w[kk] * a3[0]; o[7] += w[kk] * a3[1];
        }
        float4 xa = *(const float4*)(xr + d0);
        float4 xb = *(const float4*)(xr + d0 + 4);
        float vals[8] = { o[0] + xa.x, o[1] + xa.y, o[2] + xa.z, o[3] + xa.w,
                          o[4] + xb.x, o[5] + xb.y, o[6] + xb.z, o[7] + xb.w };
        float4 w0, w1;
        w0.x = vals[0]; w0.y = vals[1]; w0.z = vals[2]; w0.w = vals[3];
        w1.x = vals[4]; w1.y = vals[5]; w1.z = vals[6]; w1.w = vals[7];
        *(float4*)(x1r + d0) = w0;
        *(float4*)(x1r + d0 + 4) = w1;
#pragma unroll
        for (int e = 0; e < 8; ++e) {
            xv[wd * 8 + e] = vals[e];
            s += vals[e]; ss += vals[e] * vals[e];
        }
    }
#pragma unroll
    for (int o2 = 16; o2; o2 >>= 1) { s += __shfl_xor(s, o2); ss += __shfl_xor(ss, o2); }
    float mean = s * (1.f / 768.f);
    float var = (ss - 768.f * mean * mean) * (1.f / 767.f);
    float denom = sqrtf(var) + 1e-6f;
    float sc = g[0] / denom, bb = b[0] - mean * sc;
    u16* xnr = xn2 + trow * DIM;
#pragma unroll
    for (int wd = 0; wd < 3; ++wd) {
        const int d0 = wd * 256 + li * 8;
        uint4 o;
        o.x = pack2b(xv[wd * 8 + 0] * sc + bb, xv[wd * 8 + 1] * sc + bb);
        o.y = pack2b(xv[wd * 8 + 2] * sc + bb, xv[wd * 8 + 3] * sc + bb);
        o.z = pack2b(xv[wd * 8 + 4] * sc + bb, xv[wd * 8 + 5] * sc + bb);
        o.w = pack2b(xv[wd * 8 + 6] * sc + bb, xv[wd * 8 + 7] * sc + bb);
        *(uint4*)(xnr + d0) = o;
    }
}

extern "C" void kernel_launch(void* const* d_in, const int* in_sizes, int n_in,
                              void* d_out, int out_size, void* d_ws, size_t ws_size,
                              hipStream_t stream) {
    (void)n_in; (void)out_size; (void)ws_size;
    const float* x    = (const float*)d_in[0];
    const float* wq_w = (const float*)d_in[1];
    const float* wq_b = (const float*)d_in[2];
    const float* wk_w = (const float*)d_in[3];
    const float* wk_b = (const float*)d_in[4];
    const float* wv_w = (const float*)d_in[5];
    const float* wv_b = (const float*)d_in[6];
    const float* d1_w = (const float*)d_in[7];
    const float* d1_b = (const float*)d_in[8];
    const float* d2_w = (const float*)d_in[9];
    const float* d2_b = (const float*)d_in[10];
    const float* g1 = (const float*)d_in[11];
    const float* b1 = (const float*)d_in[12];
    const float* g2 = (const float*)d_in[13];
    const float* b2 = (const float*)d_in[14];
    float* out = (float*)d_out;
    char* ws = (char*)d_ws;

    const int T = in_sizes[0] / DIM;  // 16384

    // ws layout (bytes):
    u8*    w_qkv8 = (u8*)(ws);                    // [2304][768] fp8    1,769,472
    u16*   w_d1   = (u16*)(ws + 1769472);         // [3072][768] bf16   4,718,592
    u8*    w_d28  = (u8*)(ws + 6488064);          // [768][3072] fp8    2,359,296
    float* b_qkv  = (float*)(ws + 8847360);       // [2304] f32             9,216
    u16*   xn2    = (u16*)(ws + 8856576);         // [T][768] bf16     25,165,824
    float* x1     = (float*)(ws + 34022400);      // [T][768] f32      50,331,648
    u8*    xn1_8  = (u8*)(ws + 34022400);         // [T][768] fp8 — aliases x1 (dead before attn)
    u8*    qkv8   = (u8*)(ws + 84354048);         // [T][2304] fp8     37,748,736
    u8*    h8     = (u8*)(ws + 84354048);         // [T][3072] fp8 — reuses qkv region (dead after attn)

    cvt_all<<<dim3(2304, 3), 256, 0, stream>>>(
        (const float4*)wq_w, (const float4*)wk_w, (const float4*)wv_w,
        (const float4*)d1_w, (const float4*)d2_w,
        wq_b, wk_b, wv_b,
        (ushort4*)w_d1, (unsigned*)w_d28, (unsigned*)w_qkv8, b_qkv);

    ln_rows_f8<<<T / 4, 256, 0, stream>>>(x, xn1_8, g1, b1);
    gemm_f8<0, 2304, 768><<<dim3(T / 128, 18), 256, 0, stream>>>(xn1_8, w_qkv8, b_qkv, nullptr, qkv8, nullptr);
    attn_ln<<<T / 8, 256, 0, stream>>>(qkv8, x, x1, xn2, g2, b2);
    gemm_up<3072, 768><<<dim3(T / 128, 24), 256, 0, stream>>>(xn2, w_d1, d1_b, h8);
    gemm_f8<2, 768, 3072><<<dim3(T / 128, 6), 256, 0, stream>>>(h8, w_d28, d2_b, x1, nullptr, out);
}